// Round 7
// baseline (278.594 us; speedup 1.0000x reference)
//
#include <hip/hip_runtime.h>
#include <math.h>

// DifferentiableMultiMLPRenderer — round 7.
// P[v] = (feat[v]@W1a + shape[v]@W1b)/3 precomputed (pgemm). Pixel kernel:
// layer1 = blend(3 P-rows) + emb@W1e (K=64) + b1' (style folded); layer2 MFMA;
// layer3 (256->4, w3 padded to 16 cols) also MFMA. One 32KB LDS buffer serves
// blend -> h1(in-place) -> h2. 3 blocks/CU.

typedef _Float16 hv8 __attribute__((ext_vector_type(8)));
typedef __attribute__((ext_vector_type(4))) float f32x4;

#define TILE_M 64

__device__ inline int swzE(int row, int k) { return row * 64  + (k ^ ((row & 7) << 3)); }
__device__ inline int swzH(int row, int k) { return row * 256 + (k ^ ((row & 7) << 3)); }
__device__ inline int swzA(int row, int k) { return row * 384 + (k ^ ((row & 7) << 3)); }

// ---- prep: fold style into b1; build f16 weights: w1T (1/3 folded), w2T, w3T ----
__global__ __launch_bounds__(256)
void prep_weights(const float* __restrict__ style,
                  const float* __restrict__ w1, const float* __restrict__ b1,
                  const float* __restrict__ w2, const float* __restrict__ w3,
                  _Float16* __restrict__ w1T, _Float16* __restrict__ w2T,
                  _Float16* __restrict__ w3T, float* __restrict__ b1p)
{
    const int j = blockIdx.x;
    const int t = threadIdx.x;
    if (j < 256) {
        float part = style[t] * w1[(size_t)(447 + t) * 256 + j];
        #pragma unroll
        for (int off = 32; off; off >>= 1) part += __shfl_down(part, off, 64);
        __shared__ float red[4];
        if ((t & 63) == 0) red[t >> 6] = part;
        __syncthreads();
        if (t == 0) b1p[j] = b1[j] + red[0] + red[1] + red[2] + red[3];
        for (int k = t; k < 448; k += 256) {
            float v = (k < 447) ? w1[(size_t)k * 256 + j] : 0.0f;
            if (k < 384) v *= (1.0f / 3.0f);
            w1T[(size_t)j * 448 + k] = (_Float16)v;
        }
    } else if (j < 512) {
        const int jj = j - 256;
        w2T[(size_t)jj * 256 + t] = (_Float16)w2[(size_t)t * 256 + jj];
    } else {
        // w3T[16][256]: rows 0..2 = w3 columns, rows 3..15 = 0
        #pragma unroll
        for (int r = 0; r < 16; ++r)
            w3T[r * 256 + t] = (r < 3) ? (_Float16)w3[t * 3 + r] : (_Float16)0.0f;
    }
}

// ---- pgemm: P[v][j] = sum_k [feat|shape][v][k] * w1T[j][k] (1/3 folded) ----
__global__ __launch_bounds__(256, 2)
void pgemm(const float* __restrict__ feat, const float* __restrict__ shp,
           const _Float16* __restrict__ w1T, _Float16* __restrict__ P, int nV)
{
    __shared__ _Float16 as[64 * 384];   // 48 KB
    const int tid = threadIdx.x;
    const int n0 = blockIdx.x * 64;
    const int lane = tid & 63, wv = tid >> 6;
    const int nbase = wv << 6, l15 = lane & 15, kq = lane >> 4;

    const hv8* bp[4];
    #pragma unroll
    for (int nf = 0; nf < 4; ++nf)
        bp[nf] = (const hv8*)(w1T + (size_t)(nbase + nf * 16 + l15) * 448 + (kq << 3));
    hv8 bv[3][4];
    auto loadB = [&](int t, hv8* dst) {
        #pragma unroll
        for (int nf = 0; nf < 4; ++nf) dst[nf] = bp[nf][t << 2];
    };
    loadB(0, bv[0]); loadB(1, bv[1]); loadB(2, bv[2]);

    #pragma unroll
    for (int i = 0; i < 12; ++i) {
        const int id = tid + i * 256;
        const int row = id / 48;
        const int g = id - row * 48;
        int v = n0 + row; if (v >= nV) v = nV - 1;
        const float* s = (g < 32) ? (feat + (size_t)v * 256 + g * 8)
                                  : (shp  + (size_t)v * 128 + (g - 32) * 8);
        const float4 a = ((const float4*)s)[0];
        const float4 b = ((const float4*)s)[1];
        hv8 h = { (_Float16)a.x, (_Float16)a.y, (_Float16)a.z, (_Float16)a.w,
                  (_Float16)b.x, (_Float16)b.y, (_Float16)b.z, (_Float16)b.w };
        *(hv8*)(&as[swzA(row, g * 8)]) = h;
    }
    f32x4 acc[4][4];
    #pragma unroll
    for (int mf = 0; mf < 4; ++mf)
        #pragma unroll
        for (int nf = 0; nf < 4; ++nf) acc[mf][nf] = (f32x4){0.f, 0.f, 0.f, 0.f};
    __syncthreads();

    auto loadA = [&](int t, hv8* dst) {
        #pragma unroll
        for (int mf = 0; mf < 4; ++mf)
            dst[mf] = *(const hv8*)(as + swzA(mf * 16 + l15, (t << 5) | (kq << 3)));
    };
    hv8 av[2][4];
    loadA(0, av[0]);
    #pragma unroll
    for (int t = 0; t < 12; ++t) {
        if (t + 1 < 12) loadA(t + 1, av[(t + 1) & 1]);
        const hv8* avt = av[t & 1];
        const hv8* bvt = bv[t % 3];
        __builtin_amdgcn_s_setprio(1);
        #pragma unroll
        for (int mf = 0; mf < 4; ++mf)
            #pragma unroll
            for (int nf = 0; nf < 4; ++nf)
                acc[mf][nf] = __builtin_amdgcn_mfma_f32_16x16x32_f16(avt[mf], bvt[nf], acc[mf][nf], 0, 0, 0);
        __builtin_amdgcn_s_setprio(0);
        if (t + 3 < 12) loadB(t + 3, bv[t % 3]);
    }
    #pragma unroll
    for (int mf = 0; mf < 4; ++mf)
        #pragma unroll
        for (int nf = 0; nf < 4; ++nf) {
            const int col = nbase + nf * 16 + l15;
            const int r0 = mf * 16 + (kq << 2);
            #pragma unroll
            for (int r = 0; r < 4; ++r) {
                const int v = n0 + r0 + r;
                if (v < nV) P[(size_t)v * 256 + col] = (_Float16)acc[mf][nf][r];
            }
        }
}

// ---- main fused pixel kernel ----
__global__ __launch_bounds__(256, 3)
void renderer(const int* __restrict__ pix, const float* __restrict__ bary,
              const int* __restrict__ faces,
              const _Float16* __restrict__ P,
              const float* __restrict__ color_bg,
              const float* __restrict__ b2g,
              const float* __restrict__ b3,
              const _Float16* __restrict__ w1T,
              const _Float16* __restrict__ w2T,
              const _Float16* __restrict__ w3T,
              const float* __restrict__ b1p,
              float* __restrict__ out)
{
    __shared__ _Float16 embs[64 * 64];    // 8 KB
    __shared__ _Float16 pb[64 * 256];     // 32 KB: blend -> h1 (in-place) -> h2
    __shared__ int   vidx[TILE_M][3];
    __shared__ float bcs[TILE_M][3];

    const int tid = threadIdx.x;
    const int cpx = gridDim.x >> 3;
    const int bid = (blockIdx.x & 7) * cpx + (blockIdx.x >> 3);   // XCD-aware
    const int n0  = bid * TILE_M;

    const int lane  = tid & 63;
    const int wv    = tid >> 6;
    const int nbase = wv << 6;
    const int l15   = lane & 15;
    const int kq    = lane >> 4;

    if (tid < TILE_M) {
        const int n = n0 + tid;
        const int face = pix[n];
        vidx[tid][0] = faces[face * 3 + 0];
        vidx[tid][1] = faces[face * 3 + 1];
        vidx[tid][2] = faces[face * 3 + 2];
        bcs[tid][0] = bary[n * 3 + 0];
        bcs[tid][1] = bary[n * 3 + 1];
        bcs[tid][2] = bary[n * 3 + 2];
    }
    __syncthreads();

    const int gp = tid >> 5;            // 0..7 : pixel sub-slice
    const int c8 = (tid & 31) << 3;     // col chunk (32 lanes cover a 512B row)

    // --- batch A gathers (pixel rows 0..31): 12 loads, 48 VGPRs ---
    hv8 ga0[4], ga1[4], ga2[4];
    #pragma unroll
    for (int pp = 0; pp < 4; ++pp) {
        const int p = pp * 8 + gp;
        ga0[pp] = *(const hv8*)(P + (size_t)vidx[p][0] * 256 + c8);
        ga1[pp] = *(const hv8*)(P + (size_t)vidx[p][1] * 256 + c8);
        ga2[pp] = *(const hv8*)(P + (size_t)vidx[p][2] * 256 + c8);
    }

    // --- emb (NeRF embed of bary) -> embs ---
    {
        const int p = tid >> 2;
        const int e16 = (tid & 3) << 4;
        const float c0 = bcs[p][0], c1 = bcs[p][1], c2 = bcs[p][2];
        #pragma unroll
        for (int hh = 0; hh < 2; ++hh) {
            hv8 h;
            #pragma unroll
            for (int i = 0; i < 8; ++i) {
                const int s = e16 + hh * 8 + i;
                float v;
                if (s < 3) v = (s == 0) ? c0 : ((s == 1) ? c1 : c2);
                else if (s < 63) {
                    const int q = s - 3;
                    const int f = q / 6;
                    const int rem = q - f * 6;
                    const int d = (rem >= 3) ? rem - 3 : rem;
                    const float bd = (d == 0) ? c0 : ((d == 1) ? c1 : c2);
                    const float arg = bd * (float)(1 << f);
                    v = (rem < 3) ? __sinf(arg) : __cosf(arg);
                } else v = 0.0f;
                h[i] = (_Float16)v;
            }
            *(hv8*)(&embs[swzE(p, e16 + hh * 8)]) = h;
        }
    }

    // --- batch B gathers (pixel rows 32..63) ---
    hv8 gb0[4], gb1[4], gb2[4];
    #pragma unroll
    for (int pp = 0; pp < 4; ++pp) {
        const int p = (pp + 4) * 8 + gp;
        gb0[pp] = *(const hv8*)(P + (size_t)vidx[p][0] * 256 + c8);
        gb1[pp] = *(const hv8*)(P + (size_t)vidx[p][1] * 256 + c8);
        gb2[pp] = *(const hv8*)(P + (size_t)vidx[p][2] * 256 + c8);
    }
    // --- emb-weight B fragments ---
    hv8 bve[2][4];
    #pragma unroll
    for (int nf = 0; nf < 4; ++nf) {
        const hv8* bpe = (const hv8*)(w1T + (size_t)(nbase + nf * 16 + l15) * 448 + 384 + (kq << 3));
        bve[0][nf] = bpe[0];
        bve[1][nf] = bpe[4];
    }

    // --- blend batch A -> pb (waits only batch-A loads) ---
    #pragma unroll
    for (int pp = 0; pp < 4; ++pp) {
        const int p = pp * 8 + gp;
        const _Float16 c0 = (_Float16)bcs[p][0];
        const _Float16 c1 = (_Float16)bcs[p][1];
        const _Float16 c2 = (_Float16)bcs[p][2];
        *(hv8*)(&pb[swzH(p, c8)]) = ga0[pp] * c0 + ga1[pp] * c1 + ga2[pp] * c2;
    }
    __syncthreads();   // embs ready

    f32x4 acc[4][4];
    #pragma unroll
    for (int nf = 0; nf < 4; ++nf) {
        const float b = b1p[nbase + nf * 16 + l15];
        #pragma unroll
        for (int mf = 0; mf < 4; ++mf) acc[mf][nf] = (f32x4){b, b, b, b};
    }

    hv8 ave[2][4];
    #pragma unroll
    for (int t = 0; t < 2; ++t)
        #pragma unroll
        for (int mf = 0; mf < 4; ++mf)
            ave[t][mf] = *(const hv8*)(embs + swzE(mf * 16 + l15, (t << 5) | (kq << 3)));

    __builtin_amdgcn_s_setprio(1);
    #pragma unroll
    for (int mf = 0; mf < 4; ++mf)
        #pragma unroll
        for (int nf = 0; nf < 4; ++nf)
            acc[mf][nf] = __builtin_amdgcn_mfma_f32_16x16x32_f16(ave[0][mf], bve[0][nf], acc[mf][nf], 0, 0, 0);
    __builtin_amdgcn_s_setprio(0);

    // --- blend batch B -> pb ---
    #pragma unroll
    for (int pp = 0; pp < 4; ++pp) {
        const int p = (pp + 4) * 8 + gp;
        const _Float16 c0 = (_Float16)bcs[p][0];
        const _Float16 c1 = (_Float16)bcs[p][1];
        const _Float16 c2 = (_Float16)bcs[p][2];
        *(hv8*)(&pb[swzH(p, c8)]) = gb0[pp] * c0 + gb1[pp] * c1 + gb2[pp] * c2;
    }

    __builtin_amdgcn_s_setprio(1);
    #pragma unroll
    for (int mf = 0; mf < 4; ++mf)
        #pragma unroll
        for (int nf = 0; nf < 4; ++nf)
            acc[mf][nf] = __builtin_amdgcn_mfma_f32_16x16x32_f16(ave[1][mf], bve[1][nf], acc[mf][nf], 0, 0, 0);
    __builtin_amdgcn_s_setprio(0);

    // --- layer-2 B prefetch ---
    const hv8* bp2[4];
    #pragma unroll
    for (int nf = 0; nf < 4; ++nf)
        bp2[nf] = (const hv8*)(w2T + (size_t)(nbase + nf * 16 + l15) * 256 + (kq << 3));
    hv8 bv2[3][4];
    auto loadB2 = [&](int t, hv8* dst) {
        #pragma unroll
        for (int nf = 0; nf < 4; ++nf) dst[nf] = bp2[nf][t << 2];
    };
    loadB2(0, bv2[0]); loadB2(1, bv2[1]); loadB2(2, bv2[2]);
    __syncthreads();   // pb (blend) complete

    // --- layer-1 epilogue: h1 = relu(acc + pb) IN-PLACE into pb; acc = b2 ---
    #pragma unroll
    for (int mf = 0; mf < 4; ++mf)
        #pragma unroll
        for (int nf = 0; nf < 4; ++nf) {
            const int col = nbase + nf * 16 + l15;
            const int r0 = mf * 16 + (kq << 2);
            #pragma unroll
            for (int r = 0; r < 4; ++r) {
                const int sl = swzH(r0 + r, col);
                const float pv = (float)pb[sl];
                pb[sl] = (_Float16)fmaxf(acc[mf][nf][r] + pv, 0.0f);
            }
            const float b = b2g[col];
            acc[mf][nf] = (f32x4){b, b, b, b};
        }
    __syncthreads();   // h1 ready

    // --- layer-2: 8 K-tiles, A ping-pong + 3-deep B prefetch ---
    auto loadA2 = [&](int t, hv8* dst) {
        #pragma unroll
        for (int mf = 0; mf < 4; ++mf)
            dst[mf] = *(const hv8*)(pb + swzH(mf * 16 + l15, (t << 5) | (kq << 3)));
    };
    hv8 av[2][4];
    loadA2(0, av[0]);
    #pragma unroll
    for (int t = 0; t < 8; ++t) {
        if (t + 1 < 8) loadA2(t + 1, av[(t + 1) & 1]);
        const hv8* avt = av[t & 1];
        const hv8* bvt = bv2[t % 3];
        __builtin_amdgcn_s_setprio(1);
        #pragma unroll
        for (int mf = 0; mf < 4; ++mf)
            #pragma unroll
            for (int nf = 0; nf < 4; ++nf)
                acc[mf][nf] = __builtin_amdgcn_mfma_f32_16x16x32_f16(avt[mf], bvt[nf], acc[mf][nf], 0, 0, 0);
        __builtin_amdgcn_s_setprio(0);
        if (t + 3 < 8) loadB2(t + 3, bv2[t % 3]);
    }

    // --- layer-3 B fragments (w3T[16][256]) ---
    hv8 bw3[8];
    #pragma unroll
    for (int t = 0; t < 8; ++t)
        bw3[t] = *(const hv8*)(w3T + l15 * 256 + ((t << 5) | (kq << 3)));

    __syncthreads();   // all layer-2 A-reads done
    // --- h2 = relu(acc) -> pb ---
    #pragma unroll
    for (int mf = 0; mf < 4; ++mf)
        #pragma unroll
        for (int nf = 0; nf < 4; ++nf) {
            const int col = nbase + nf * 16 + l15;
            const int r0 = mf * 16 + (kq << 2);
            #pragma unroll
            for (int r = 0; r < 4; ++r)
                pb[swzH(r0 + r, col)] = (_Float16)fmaxf(acc[mf][nf][r], 0.0f);
        }
    __syncthreads();

    // --- layer-3 MFMA: wave wv handles pixel rows [wv*16, wv*16+16) ---
    f32x4 acc3 = (f32x4){0.f, 0.f, 0.f, 0.f};
    #pragma unroll
    for (int t = 0; t < 8; ++t) {
        const hv8 av3 = *(const hv8*)(pb + swzH((wv << 4) + l15, (t << 5) | (kq << 3)));
        acc3 = __builtin_amdgcn_mfma_f32_16x16x32_f16(av3, bw3[t], acc3, 0, 0, 0);
    }
    // C: col = l15 (channel), row = kq*4 + r (pixel within wave's 16)
    if (l15 < 4) {
        const int ch = l15;
        #pragma unroll
        for (int r = 0; r < 4; ++r) {
            const int p = (wv << 4) + (kq << 2) + r;
            const int n = n0 + p;
            const bool m = pix[n] > 0;
            float v;
            if (ch == 3) v = m ? 1.0f : 0.0f;
            else         v = m ? (fmaxf(acc3[r] + b3[ch], 0.0f) - 1.0f)
                               : color_bg[(n >> 16) * 3 + ch];
            out[(size_t)n * 4 + ch] = v;
        }
    }
}

extern "C" void kernel_launch(void* const* d_in, const int* in_sizes, int n_in,
                              void* d_out, int out_size, void* d_ws, size_t ws_size,
                              hipStream_t stream) {
    const int*   pix      = (const int*)  d_in[0];
    const float* bary     = (const float*)d_in[1];
    const int*   faces    = (const int*)  d_in[2];
    const float* feature  = (const float*)d_in[3];
    const float* shapef   = (const float*)d_in[4];
    const float* color_bg = (const float*)d_in[5];
    const float* style    = (const float*)d_in[6];
    const float* w1       = (const float*)d_in[7];
    const float* b1       = (const float*)d_in[8];
    const float* w2       = (const float*)d_in[9];
    const float* b2       = (const float*)d_in[10];
    const float* w3       = (const float*)d_in[11];
    const float* b3       = (const float*)d_in[12];
    float* out = (float*)d_out;

    const int nV = in_sizes[3] / 256;                         // 50000 vertices

    char* ws = (char*)d_ws;
    _Float16* w1T  = (_Float16*)ws;                           // 229,376 B
    _Float16* w2T  = (_Float16*)(ws + 229376);                // 131,072 B
    float*    b1p  = (float*)   (ws + 360448);                // 1,024 B
    _Float16* w3T  = (_Float16*)(ws + 361472);                // 8,192 B
    _Float16* Ptab = (_Float16*)(ws + 369664);                // nV*256*2 = 25.6 MB

    hipLaunchKernelGGL(prep_weights, dim3(513), dim3(256), 0, stream,
                       style, w1, b1, w2, w3, w1T, w2T, w3T, b1p);
    hipLaunchKernelGGL(pgemm, dim3((nV + 63) / 64), dim3(256), 0, stream,
                       feature, shapef, w1T, Ptab, nV);

    const int npix = in_sizes[0];                             // 262144
    hipLaunchKernelGGL(renderer, dim3(npix / TILE_M), dim3(256), 0, stream,
                       pix, bary, faces, Ptab, color_bg,
                       b2, b3, w1T, w2T, w3T, b1p, out);
}

// Round 8
// 244.713 us; speedup vs baseline: 1.1385x; 1.1385x over previous
//
#include <hip/hip_runtime.h>
#include <math.h>

// DifferentiableMultiMLPRenderer — round 8.
// P[v] = (feat[v]@W1a + shape[v]@W1b)/3 precomputed (pgemm). Pixel kernel:
// layer1 = blend(3 P-rows) + emb@W1e (K=64) + b1' (style folded); layer2 MFMA;
// layer3 (256->4, w3T padded) MFMA. 42.5KB LDS -> 3 blocks/CU. Gathers pipelined
// in 4 batches of 6 loads (48 VGPR peak; r7's 24-reg batch spilled at the
// launch_bounds(256,3) budget -> 391MB scratch traffic. Fixed here).

typedef _Float16 hv8 __attribute__((ext_vector_type(8)));
typedef __attribute__((ext_vector_type(4))) float f32x4;

#define TILE_M 64

__device__ inline int swzE(int row, int k) { return row * 64  + (k ^ ((row & 7) << 3)); }
__device__ inline int swzH(int row, int k) { return row * 256 + (k ^ ((row & 7) << 3)); }
__device__ inline int swzA(int row, int k) { return row * 384 + (k ^ ((row & 7) << 3)); }

// ---- prep: fold style into b1; build f16 weights: w1T (1/3 folded), w2T, w3T ----
__global__ __launch_bounds__(256)
void prep_weights(const float* __restrict__ style,
                  const float* __restrict__ w1, const float* __restrict__ b1,
                  const float* __restrict__ w2, const float* __restrict__ w3,
                  _Float16* __restrict__ w1T, _Float16* __restrict__ w2T,
                  _Float16* __restrict__ w3T, float* __restrict__ b1p)
{
    const int j = blockIdx.x;
    const int t = threadIdx.x;
    if (j < 256) {
        float part = style[t] * w1[(size_t)(447 + t) * 256 + j];
        #pragma unroll
        for (int off = 32; off; off >>= 1) part += __shfl_down(part, off, 64);
        __shared__ float red[4];
        if ((t & 63) == 0) red[t >> 6] = part;
        __syncthreads();
        if (t == 0) b1p[j] = b1[j] + red[0] + red[1] + red[2] + red[3];
        for (int k = t; k < 448; k += 256) {
            float v = (k < 447) ? w1[(size_t)k * 256 + j] : 0.0f;
            if (k < 384) v *= (1.0f / 3.0f);
            w1T[(size_t)j * 448 + k] = (_Float16)v;
        }
    } else if (j < 512) {
        const int jj = j - 256;
        w2T[(size_t)jj * 256 + t] = (_Float16)w2[(size_t)t * 256 + jj];
    } else {
        #pragma unroll
        for (int r = 0; r < 16; ++r)
            w3T[r * 256 + t] = (r < 3) ? (_Float16)w3[t * 3 + r] : (_Float16)0.0f;
    }
}

// ---- pgemm: P[v][j] = sum_k [feat|shape][v][k] * w1T[j][k] (1/3 folded) ----
__global__ __launch_bounds__(256, 2)
void pgemm(const float* __restrict__ feat, const float* __restrict__ shp,
           const _Float16* __restrict__ w1T, _Float16* __restrict__ P, int nV)
{
    __shared__ _Float16 as[64 * 384];   // 48 KB
    const int tid = threadIdx.x;
    const int n0 = blockIdx.x * 64;
    const int lane = tid & 63, wv = tid >> 6;
    const int nbase = wv << 6, l15 = lane & 15, kq = lane >> 4;

    const hv8* bp[4];
    #pragma unroll
    for (int nf = 0; nf < 4; ++nf)
        bp[nf] = (const hv8*)(w1T + (size_t)(nbase + nf * 16 + l15) * 448 + (kq << 3));
    hv8 bv[3][4];
    auto loadB = [&](int t, hv8* dst) {
        #pragma unroll
        for (int nf = 0; nf < 4; ++nf) dst[nf] = bp[nf][t << 2];
    };
    loadB(0, bv[0]); loadB(1, bv[1]); loadB(2, bv[2]);

    #pragma unroll
    for (int i = 0; i < 12; ++i) {
        const int id = tid + i * 256;
        const int row = id / 48;
        const int g = id - row * 48;
        int v = n0 + row; if (v >= nV) v = nV - 1;
        const float* s = (g < 32) ? (feat + (size_t)v * 256 + g * 8)
                                  : (shp  + (size_t)v * 128 + (g - 32) * 8);
        const float4 a = ((const float4*)s)[0];
        const float4 b = ((const float4*)s)[1];
        hv8 h = { (_Float16)a.x, (_Float16)a.y, (_Float16)a.z, (_Float16)a.w,
                  (_Float16)b.x, (_Float16)b.y, (_Float16)b.z, (_Float16)b.w };
        *(hv8*)(&as[swzA(row, g * 8)]) = h;
    }
    f32x4 acc[4][4];
    #pragma unroll
    for (int mf = 0; mf < 4; ++mf)
        #pragma unroll
        for (int nf = 0; nf < 4; ++nf) acc[mf][nf] = (f32x4){0.f, 0.f, 0.f, 0.f};
    __syncthreads();

    auto loadA = [&](int t, hv8* dst) {
        #pragma unroll
        for (int mf = 0; mf < 4; ++mf)
            dst[mf] = *(const hv8*)(as + swzA(mf * 16 + l15, (t << 5) | (kq << 3)));
    };
    hv8 av[2][4];
    loadA(0, av[0]);
    #pragma unroll
    for (int t = 0; t < 12; ++t) {
        if (t + 1 < 12) loadA(t + 1, av[(t + 1) & 1]);
        const hv8* avt = av[t & 1];
        const hv8* bvt = bv[t % 3];
        __builtin_amdgcn_s_setprio(1);
        #pragma unroll
        for (int mf = 0; mf < 4; ++mf)
            #pragma unroll
            for (int nf = 0; nf < 4; ++nf)
                acc[mf][nf] = __builtin_amdgcn_mfma_f32_16x16x32_f16(avt[mf], bvt[nf], acc[mf][nf], 0, 0, 0);
        __builtin_amdgcn_s_setprio(0);
        if (t + 3 < 12) loadB(t + 3, bv[t % 3]);
    }
    #pragma unroll
    for (int mf = 0; mf < 4; ++mf)
        #pragma unroll
        for (int nf = 0; nf < 4; ++nf) {
            const int col = nbase + nf * 16 + l15;
            const int r0 = mf * 16 + (kq << 2);
            #pragma unroll
            for (int r = 0; r < 4; ++r) {
                const int v = n0 + r0 + r;
                if (v < nV) P[(size_t)v * 256 + col] = (_Float16)acc[mf][nf][r];
            }
        }
}

// ---- main fused pixel kernel ----
__global__ __launch_bounds__(256, 3)
void renderer(const int* __restrict__ pix, const float* __restrict__ bary,
              const int* __restrict__ faces,
              const _Float16* __restrict__ P,
              const float* __restrict__ color_bg,
              const float* __restrict__ b2g,
              const float* __restrict__ b3,
              const _Float16* __restrict__ w1T,
              const _Float16* __restrict__ w2T,
              const _Float16* __restrict__ w3T,
              const float* __restrict__ b1p,
              float* __restrict__ out)
{
    __shared__ _Float16 embs[64 * 64];    // 8 KB
    __shared__ _Float16 pb[64 * 256];     // 32 KB: blend -> h1 (in-place) -> h2
    __shared__ int   vidx[TILE_M][3];
    __shared__ float bcs[TILE_M][3];

    const int tid = threadIdx.x;
    const int cpx = gridDim.x >> 3;
    const int bid = (blockIdx.x & 7) * cpx + (blockIdx.x >> 3);   // XCD-aware
    const int n0  = bid * TILE_M;

    const int lane  = tid & 63;
    const int wv    = tid >> 6;
    const int nbase = wv << 6;
    const int l15   = lane & 15;
    const int kq    = lane >> 4;

    if (tid < TILE_M) {
        const int n = n0 + tid;
        const int face = pix[n];
        vidx[tid][0] = faces[face * 3 + 0];
        vidx[tid][1] = faces[face * 3 + 1];
        vidx[tid][2] = faces[face * 3 + 2];
        bcs[tid][0] = bary[n * 3 + 0];
        bcs[tid][1] = bary[n * 3 + 1];
        bcs[tid][2] = bary[n * 3 + 2];
    }
    __syncthreads();

    const int gp = tid >> 5;            // 0..7 : pixel sub-slice
    const int c8 = (tid & 31) << 3;     // col chunk (32 lanes cover a 512B row)

    // gather pipeline: 4 batches x 6 loads (16 px each); 2 named arrays, static idx
    hv8 gA[6], gB[6];
    auto loadG = [&](hv8* g, const int b) {
        #pragma unroll
        for (int j = 0; j < 2; ++j) {
            const int p = (2 * b + j) * 8 + gp;
            g[j * 3 + 0] = *(const hv8*)(P + (size_t)vidx[p][0] * 256 + c8);
            g[j * 3 + 1] = *(const hv8*)(P + (size_t)vidx[p][1] * 256 + c8);
            g[j * 3 + 2] = *(const hv8*)(P + (size_t)vidx[p][2] * 256 + c8);
        }
    };
    auto blendG = [&](hv8* g, const int b) {
        #pragma unroll
        for (int j = 0; j < 2; ++j) {
            const int p = (2 * b + j) * 8 + gp;
            const _Float16 c0 = (_Float16)bcs[p][0];
            const _Float16 c1 = (_Float16)bcs[p][1];
            const _Float16 c2 = (_Float16)bcs[p][2];
            *(hv8*)(&pb[swzH(p, c8)]) = g[j * 3 + 0] * c0 + g[j * 3 + 1] * c1 + g[j * 3 + 2] * c2;
        }
    };

    loadG(gA, 0);
    loadG(gB, 1);

    // --- emb (NeRF embed of bary) -> embs; VALU hides batch-0/1 gather latency ---
    {
        const int p = tid >> 2;
        const int e16 = (tid & 3) << 4;
        const float c0 = bcs[p][0], c1 = bcs[p][1], c2 = bcs[p][2];
        #pragma unroll
        for (int hh = 0; hh < 2; ++hh) {
            hv8 h;
            #pragma unroll
            for (int i = 0; i < 8; ++i) {
                const int s = e16 + hh * 8 + i;
                float v;
                if (s < 3) v = (s == 0) ? c0 : ((s == 1) ? c1 : c2);
                else if (s < 63) {
                    const int q = s - 3;
                    const int f = q / 6;
                    const int rem = q - f * 6;
                    const int d = (rem >= 3) ? rem - 3 : rem;
                    const float bd = (d == 0) ? c0 : ((d == 1) ? c1 : c2);
                    const float arg = bd * (float)(1 << f);
                    v = (rem < 3) ? __sinf(arg) : __cosf(arg);
                } else v = 0.0f;
                h[i] = (_Float16)v;
            }
            *(hv8*)(&embs[swzE(p, e16 + hh * 8)]) = h;
        }
    }

    blendG(gA, 0); loadG(gA, 2);
    blendG(gB, 1); loadG(gB, 3);

    // --- emb-weight B fragments ---
    hv8 bve[2][4];
    #pragma unroll
    for (int nf = 0; nf < 4; ++nf) {
        const hv8* bpe = (const hv8*)(w1T + (size_t)(nbase + nf * 16 + l15) * 448 + 384 + (kq << 3));
        bve[0][nf] = bpe[0];
        bve[1][nf] = bpe[4];
    }

    blendG(gA, 2);
    blendG(gB, 3);

    f32x4 acc[4][4];
    #pragma unroll
    for (int nf = 0; nf < 4; ++nf) {
        const float b = b1p[nbase + nf * 16 + l15];
        #pragma unroll
        for (int mf = 0; mf < 4; ++mf) acc[mf][nf] = (f32x4){b, b, b, b};
    }
    __syncthreads();   // embs + pb(blend) ready

    // --- layer-1 emb MFMA (2 tiles) ---
    hv8 ave[2][4];
    #pragma unroll
    for (int t = 0; t < 2; ++t)
        #pragma unroll
        for (int mf = 0; mf < 4; ++mf)
            ave[t][mf] = *(const hv8*)(embs + swzE(mf * 16 + l15, (t << 5) | (kq << 3)));

    __builtin_amdgcn_s_setprio(1);
    #pragma unroll
    for (int t = 0; t < 2; ++t)
        #pragma unroll
        for (int mf = 0; mf < 4; ++mf)
            #pragma unroll
            for (int nf = 0; nf < 4; ++nf)
                acc[mf][nf] = __builtin_amdgcn_mfma_f32_16x16x32_f16(ave[t][mf], bve[t][nf], acc[mf][nf], 0, 0, 0);
    __builtin_amdgcn_s_setprio(0);

    // --- layer-2 B prefetch ---
    const hv8* bp2[4];
    #pragma unroll
    for (int nf = 0; nf < 4; ++nf)
        bp2[nf] = (const hv8*)(w2T + (size_t)(nbase + nf * 16 + l15) * 256 + (kq << 3));
    hv8 bv2[3][4];
    auto loadB2 = [&](int t, hv8* dst) {
        #pragma unroll
        for (int nf = 0; nf < 4; ++nf) dst[nf] = bp2[nf][t << 2];
    };
    loadB2(0, bv2[0]); loadB2(1, bv2[1]); loadB2(2, bv2[2]);

    // --- layer-1 epilogue: h1 = relu(acc + pb) IN-PLACE; acc = b2 ---
    #pragma unroll
    for (int mf = 0; mf < 4; ++mf)
        #pragma unroll
        for (int nf = 0; nf < 4; ++nf) {
            const int col = nbase + nf * 16 + l15;
            const int r0 = mf * 16 + (kq << 2);
            #pragma unroll
            for (int r = 0; r < 4; ++r) {
                const int sl = swzH(r0 + r, col);
                const float pv = (float)pb[sl];
                pb[sl] = (_Float16)fmaxf(acc[mf][nf][r] + pv, 0.0f);
            }
            const float b = b2g[col];
            acc[mf][nf] = (f32x4){b, b, b, b};
        }
    __syncthreads();   // h1 ready

    // --- layer-2: 8 K-tiles, A ping-pong + 3-deep B prefetch ---
    auto loadA2 = [&](int t, hv8* dst) {
        #pragma unroll
        for (int mf = 0; mf < 4; ++mf)
            dst[mf] = *(const hv8*)(pb + swzH(mf * 16 + l15, (t << 5) | (kq << 3)));
    };
    hv8 av[2][4];
    loadA2(0, av[0]);
    #pragma unroll
    for (int t = 0; t < 8; ++t) {
        if (t + 1 < 8) loadA2(t + 1, av[(t + 1) & 1]);
        const hv8* avt = av[t & 1];
        const hv8* bvt = bv2[t % 3];
        __builtin_amdgcn_s_setprio(1);
        #pragma unroll
        for (int mf = 0; mf < 4; ++mf)
            #pragma unroll
            for (int nf = 0; nf < 4; ++nf)
                acc[mf][nf] = __builtin_amdgcn_mfma_f32_16x16x32_f16(avt[mf], bvt[nf], acc[mf][nf], 0, 0, 0);
        __builtin_amdgcn_s_setprio(0);
        if (t + 3 < 8) loadB2(t + 3, bv2[t % 3]);
    }

    // --- layer-3 B fragments (w3T[16][256]) ---
    hv8 bw3[8];
    #pragma unroll
    for (int t = 0; t < 8; ++t)
        bw3[t] = *(const hv8*)(w3T + l15 * 256 + ((t << 5) | (kq << 3)));

    __syncthreads();   // all layer-2 A-reads done
    // --- h2 = relu(acc) -> pb ---
    #pragma unroll
    for (int mf = 0; mf < 4; ++mf)
        #pragma unroll
        for (int nf = 0; nf < 4; ++nf) {
            const int col = nbase + nf * 16 + l15;
            const int r0 = mf * 16 + (kq << 2);
            #pragma unroll
            for (int r = 0; r < 4; ++r)
                pb[swzH(r0 + r, col)] = (_Float16)fmaxf(acc[mf][nf][r], 0.0f);
        }
    __syncthreads();

    // --- layer-3 MFMA: wave wv handles pixel rows [wv*16, wv*16+16) ---
    f32x4 acc3 = (f32x4){0.f, 0.f, 0.f, 0.f};
    #pragma unroll
    for (int t = 0; t < 8; ++t) {
        const hv8 av3 = *(const hv8*)(pb + swzH((wv << 4) + l15, (t << 5) | (kq << 3)));
        acc3 = __builtin_amdgcn_mfma_f32_16x16x32_f16(av3, bw3[t], acc3, 0, 0, 0);
    }
    if (l15 < 4) {
        const int ch = l15;
        #pragma unroll
        for (int r = 0; r < 4; ++r) {
            const int p = (wv << 4) + (kq << 2) + r;
            const int n = n0 + p;
            const bool m = pix[n] > 0;
            float v;
            if (ch == 3) v = m ? 1.0f : 0.0f;
            else         v = m ? (fmaxf(acc3[r] + b3[ch], 0.0f) - 1.0f)
                               : color_bg[(n >> 16) * 3 + ch];
            out[(size_t)n * 4 + ch] = v;
        }
    }
}

extern "C" void kernel_launch(void* const* d_in, const int* in_sizes, int n_in,
                              void* d_out, int out_size, void* d_ws, size_t ws_size,
                              hipStream_t stream) {
    const int*   pix      = (const int*)  d_in[0];
    const float* bary     = (const float*)d_in[1];
    const int*   faces    = (const int*)  d_in[2];
    const float* feature  = (const float*)d_in[3];
    const float* shapef   = (const float*)d_in[4];
    const float* color_bg = (const float*)d_in[5];
    const float* style    = (const float*)d_in[6];
    const float* w1       = (const float*)d_in[7];
    const float* b1       = (const float*)d_in[8];
    const float* w2       = (const float*)d_in[9];
    const float* b2       = (const float*)d_in[10];
    const float* w3       = (const float*)d_in[11];
    const float* b3       = (const float*)d_in[12];
    float* out = (float*)d_out;

    const int nV = in_sizes[3] / 256;                         // 50000 vertices

    char* ws = (char*)d_ws;
    _Float16* w1T  = (_Float16*)ws;                           // 229,376 B
    _Float16* w2T  = (_Float16*)(ws + 229376);                // 131,072 B
    float*    b1p  = (float*)   (ws + 360448);                // 1,024 B
    _Float16* w3T  = (_Float16*)(ws + 361472);                // 8,192 B
    _Float16* Ptab = (_Float16*)(ws + 369664);                // nV*256*2 = 25.6 MB

    hipLaunchKernelGGL(prep_weights, dim3(513), dim3(256), 0, stream,
                       style, w1, b1, w2, w3, w1T, w2T, w3T, b1p);
    hipLaunchKernelGGL(pgemm, dim3((nV + 63) / 64), dim3(256), 0, stream,
                       feature, shapef, w1T, Ptab, nV);

    const int npix = in_sizes[0];                             // 262144
    hipLaunchKernelGGL(renderer, dim3(npix / TILE_M), dim3(256), 0, stream,
                       pix, bary, faces, Ptab, color_bg,
                       b2, b3, w1T, w2T, w3T, b1p, out);
}

// Round 9
// 233.385 us; speedup vs baseline: 1.1937x; 1.0485x over previous
//
#include <hip/hip_runtime.h>
#include <math.h>

// DifferentiableMultiMLPRenderer — round 9: spill-free 3-blocks/CU.
// P[v] = (feat[v]@W1a + shape[v]@W1b)/3 precomputed (pgemm). Pixel kernel:
// layer1 = blend(3 P-rows) + emb@W1e (K=64) + b1'; layer2 MFMA; layer3 MFMA.
// Register budget at launch_bounds(256,3): 168 unified - 64 AGPR = ~104 arch.
// Gathers: 8 batches x 8 px, 2-deep ping-pong (2 x 24 VGPR). bv2 prefetch depth 2.

typedef _Float16 hv8 __attribute__((ext_vector_type(8)));
typedef __attribute__((ext_vector_type(4))) float f32x4;

#define TILE_M 64

__device__ inline int swzE(int row, int k) { return row * 64  + (k ^ ((row & 7) << 3)); }
__device__ inline int swzH(int row, int k) { return row * 256 + (k ^ ((row & 7) << 3)); }
__device__ inline int swzA(int row, int k) { return row * 384 + (k ^ ((row & 7) << 3)); }

// ---- prep: fold style into b1; build f16 weights: w1T (1/3 folded), w2T, w3T ----
__global__ __launch_bounds__(256)
void prep_weights(const float* __restrict__ style,
                  const float* __restrict__ w1, const float* __restrict__ b1,
                  const float* __restrict__ w2, const float* __restrict__ w3,
                  _Float16* __restrict__ w1T, _Float16* __restrict__ w2T,
                  _Float16* __restrict__ w3T, float* __restrict__ b1p)
{
    const int j = blockIdx.x;
    const int t = threadIdx.x;
    if (j < 256) {
        float part = style[t] * w1[(size_t)(447 + t) * 256 + j];
        #pragma unroll
        for (int off = 32; off; off >>= 1) part += __shfl_down(part, off, 64);
        __shared__ float red[4];
        if ((t & 63) == 0) red[t >> 6] = part;
        __syncthreads();
        if (t == 0) b1p[j] = b1[j] + red[0] + red[1] + red[2] + red[3];
        for (int k = t; k < 448; k += 256) {
            float v = (k < 447) ? w1[(size_t)k * 256 + j] : 0.0f;
            if (k < 384) v *= (1.0f / 3.0f);
            w1T[(size_t)j * 448 + k] = (_Float16)v;
        }
    } else if (j < 512) {
        const int jj = j - 256;
        w2T[(size_t)jj * 256 + t] = (_Float16)w2[(size_t)t * 256 + jj];
    } else {
        #pragma unroll
        for (int r = 0; r < 16; ++r)
            w3T[r * 256 + t] = (r < 3) ? (_Float16)w3[t * 3 + r] : (_Float16)0.0f;
    }
}

// ---- pgemm: P[v][j] = sum_k [feat|shape][v][k] * w1T[j][k] (1/3 folded) ----
__global__ __launch_bounds__(256, 2)
void pgemm(const float* __restrict__ feat, const float* __restrict__ shp,
           const _Float16* __restrict__ w1T, _Float16* __restrict__ P, int nV)
{
    __shared__ _Float16 as[64 * 384];   // 48 KB
    const int tid = threadIdx.x;
    const int n0 = blockIdx.x * 64;
    const int lane = tid & 63, wv = tid >> 6;
    const int nbase = wv << 6, l15 = lane & 15, kq = lane >> 4;

    const hv8* bp[4];
    #pragma unroll
    for (int nf = 0; nf < 4; ++nf)
        bp[nf] = (const hv8*)(w1T + (size_t)(nbase + nf * 16 + l15) * 448 + (kq << 3));
    hv8 bv[3][4];
    auto loadB = [&](int t, hv8* dst) {
        #pragma unroll
        for (int nf = 0; nf < 4; ++nf) dst[nf] = bp[nf][t << 2];
    };
    loadB(0, bv[0]); loadB(1, bv[1]); loadB(2, bv[2]);

    #pragma unroll
    for (int i = 0; i < 12; ++i) {
        const int id = tid + i * 256;
        const int row = id / 48;
        const int g = id - row * 48;
        int v = n0 + row; if (v >= nV) v = nV - 1;
        const float* s = (g < 32) ? (feat + (size_t)v * 256 + g * 8)
                                  : (shp  + (size_t)v * 128 + (g - 32) * 8);
        const float4 a = ((const float4*)s)[0];
        const float4 b = ((const float4*)s)[1];
        hv8 h = { (_Float16)a.x, (_Float16)a.y, (_Float16)a.z, (_Float16)a.w,
                  (_Float16)b.x, (_Float16)b.y, (_Float16)b.z, (_Float16)b.w };
        *(hv8*)(&as[swzA(row, g * 8)]) = h;
    }
    f32x4 acc[4][4];
    #pragma unroll
    for (int mf = 0; mf < 4; ++mf)
        #pragma unroll
        for (int nf = 0; nf < 4; ++nf) acc[mf][nf] = (f32x4){0.f, 0.f, 0.f, 0.f};
    __syncthreads();

    auto loadA = [&](int t, hv8* dst) {
        #pragma unroll
        for (int mf = 0; mf < 4; ++mf)
            dst[mf] = *(const hv8*)(as + swzA(mf * 16 + l15, (t << 5) | (kq << 3)));
    };
    hv8 av[2][4];
    loadA(0, av[0]);
    #pragma unroll
    for (int t = 0; t < 12; ++t) {
        if (t + 1 < 12) loadA(t + 1, av[(t + 1) & 1]);
        const hv8* avt = av[t & 1];
        const hv8* bvt = bv[t % 3];
        __builtin_amdgcn_s_setprio(1);
        #pragma unroll
        for (int mf = 0; mf < 4; ++mf)
            #pragma unroll
            for (int nf = 0; nf < 4; ++nf)
                acc[mf][nf] = __builtin_amdgcn_mfma_f32_16x16x32_f16(avt[mf], bvt[nf], acc[mf][nf], 0, 0, 0);
        __builtin_amdgcn_s_setprio(0);
        if (t + 3 < 12) loadB(t + 3, bv[t % 3]);
    }
    #pragma unroll
    for (int mf = 0; mf < 4; ++mf)
        #pragma unroll
        for (int nf = 0; nf < 4; ++nf) {
            const int col = nbase + nf * 16 + l15;
            const int r0 = mf * 16 + (kq << 2);
            #pragma unroll
            for (int r = 0; r < 4; ++r) {
                const int v = n0 + r0 + r;
                if (v < nV) P[(size_t)v * 256 + col] = (_Float16)acc[mf][nf][r];
            }
        }
}

// ---- main fused pixel kernel ----
__global__ __launch_bounds__(256, 3)
void renderer(const int* __restrict__ pix, const float* __restrict__ bary,
              const int* __restrict__ faces,
              const _Float16* __restrict__ P,
              const float* __restrict__ color_bg,
              const float* __restrict__ b2g,
              const float* __restrict__ b3,
              const _Float16* __restrict__ w1T,
              const _Float16* __restrict__ w2T,
              const _Float16* __restrict__ w3T,
              const float* __restrict__ b1p,
              float* __restrict__ out)
{
    __shared__ _Float16 embs[64 * 64];    // 8 KB
    __shared__ _Float16 pb[64 * 256];     // 32 KB: blend -> h1 (in-place) -> h2
    __shared__ int   vidx[TILE_M][3];
    __shared__ float bcs[TILE_M][3];

    const int tid = threadIdx.x;
    const int cpx = gridDim.x >> 3;
    const int bid = (blockIdx.x & 7) * cpx + (blockIdx.x >> 3);   // XCD-aware
    const int n0  = bid * TILE_M;

    const int lane  = tid & 63;
    const int wv    = tid >> 6;
    const int nbase = wv << 6;
    const int l15   = lane & 15;
    const int kq    = lane >> 4;

    if (tid < TILE_M) {
        const int n = n0 + tid;
        const int face = pix[n];
        vidx[tid][0] = faces[face * 3 + 0];
        vidx[tid][1] = faces[face * 3 + 1];
        vidx[tid][2] = faces[face * 3 + 2];
        bcs[tid][0] = bary[n * 3 + 0];
        bcs[tid][1] = bary[n * 3 + 1];
        bcs[tid][2] = bary[n * 3 + 2];
    }
    __syncthreads();

    const int gp = tid >> 5;            // 0..7 : pixel within batch
    const int c8 = (tid & 31) << 3;     // col chunk (32 lanes cover a 512B row)

    // gather: 8 batches x 8 px; 2-deep ping-pong, 24 VGPR per slot (48 peak)
    hv8 g0[3], g1[3];
    auto loadG = [&](hv8* g, const int b) {
        const int p = b * 8 + gp;
        g[0] = *(const hv8*)(P + (size_t)vidx[p][0] * 256 + c8);
        g[1] = *(const hv8*)(P + (size_t)vidx[p][1] * 256 + c8);
        g[2] = *(const hv8*)(P + (size_t)vidx[p][2] * 256 + c8);
    };
    auto blendG = [&](hv8* g, const int b) {
        const int p = b * 8 + gp;
        const _Float16 c0 = (_Float16)bcs[p][0];
        const _Float16 c1 = (_Float16)bcs[p][1];
        const _Float16 c2 = (_Float16)bcs[p][2];
        *(hv8*)(&pb[swzH(p, c8)]) = g[0] * c0 + g[1] * c1 + g[2] * c2;
    };

    loadG(g0, 0);
    loadG(g1, 1);

    // --- emb (NeRF embed of bary) -> embs; VALU hides batch-0/1 gather latency ---
    {
        const int p = tid >> 2;
        const int e16 = (tid & 3) << 4;
        const float c0 = bcs[p][0], c1 = bcs[p][1], c2 = bcs[p][2];
        #pragma unroll
        for (int hh = 0; hh < 2; ++hh) {
            hv8 h;
            #pragma unroll
            for (int i = 0; i < 8; ++i) {
                const int s = e16 + hh * 8 + i;
                float v;
                if (s < 3) v = (s == 0) ? c0 : ((s == 1) ? c1 : c2);
                else if (s < 63) {
                    const int q = s - 3;
                    const int f = q / 6;
                    const int rem = q - f * 6;
                    const int d = (rem >= 3) ? rem - 3 : rem;
                    const float bd = (d == 0) ? c0 : ((d == 1) ? c1 : c2);
                    const float arg = bd * (float)(1 << f);
                    v = (rem < 3) ? __sinf(arg) : __cosf(arg);
                } else v = 0.0f;
                h[i] = (_Float16)v;
            }
            *(hv8*)(&embs[swzE(p, e16 + hh * 8)]) = h;
        }
    }

    // drain the pipeline: blend b, immediately re-issue b+2 into the freed slot
    blendG(g0, 0); loadG(g0, 2);
    blendG(g1, 1); loadG(g1, 3);
    blendG(g0, 2); loadG(g0, 4);
    blendG(g1, 3); loadG(g1, 5);
    blendG(g0, 4); loadG(g0, 6);
    blendG(g1, 5); loadG(g1, 7);
    blendG(g0, 6);
    blendG(g1, 7);

    // --- emb-weight B fragments (after gather window to keep reg peak low) ---
    hv8 bve[2][4];
    #pragma unroll
    for (int nf = 0; nf < 4; ++nf) {
        const hv8* bpe = (const hv8*)(w1T + (size_t)(nbase + nf * 16 + l15) * 448 + 384 + (kq << 3));
        bve[0][nf] = bpe[0];
        bve[1][nf] = bpe[4];
    }

    f32x4 acc[4][4];
    #pragma unroll
    for (int nf = 0; nf < 4; ++nf) {
        const float b = b1p[nbase + nf * 16 + l15];
        #pragma unroll
        for (int mf = 0; mf < 4; ++mf) acc[mf][nf] = (f32x4){b, b, b, b};
    }
    __syncthreads();   // embs + pb(blend) ready

    // --- layer-1 emb MFMA (2 tiles) ---
    hv8 ave[2][4];
    #pragma unroll
    for (int t = 0; t < 2; ++t)
        #pragma unroll
        for (int mf = 0; mf < 4; ++mf)
            ave[t][mf] = *(const hv8*)(embs + swzE(mf * 16 + l15, (t << 5) | (kq << 3)));

    __builtin_amdgcn_s_setprio(1);
    #pragma unroll
    for (int t = 0; t < 2; ++t)
        #pragma unroll
        for (int mf = 0; mf < 4; ++mf)
            #pragma unroll
            for (int nf = 0; nf < 4; ++nf)
                acc[mf][nf] = __builtin_amdgcn_mfma_f32_16x16x32_f16(ave[t][mf], bve[t][nf], acc[mf][nf], 0, 0, 0);
    __builtin_amdgcn_s_setprio(0);

    // --- layer-2 B prefetch (depth 2) ---
    const hv8* bp2[4];
    #pragma unroll
    for (int nf = 0; nf < 4; ++nf)
        bp2[nf] = (const hv8*)(w2T + (size_t)(nbase + nf * 16 + l15) * 256 + (kq << 3));
    hv8 bv2[2][4];
    auto loadB2 = [&](int t, hv8* dst) {
        #pragma unroll
        for (int nf = 0; nf < 4; ++nf) dst[nf] = bp2[nf][t << 2];
    };
    loadB2(0, bv2[0]); loadB2(1, bv2[1]);

    // --- layer-1 epilogue: h1 = relu(acc + pb) IN-PLACE; acc = b2 ---
    #pragma unroll
    for (int mf = 0; mf < 4; ++mf)
        #pragma unroll
        for (int nf = 0; nf < 4; ++nf) {
            const int col = nbase + nf * 16 + l15;
            const int r0 = mf * 16 + (kq << 2);
            #pragma unroll
            for (int r = 0; r < 4; ++r) {
                const int sl = swzH(r0 + r, col);
                const float pv = (float)pb[sl];
                pb[sl] = (_Float16)fmaxf(acc[mf][nf][r] + pv, 0.0f);
            }
            const float b = b2g[col];
            acc[mf][nf] = (f32x4){b, b, b, b};
        }
    __syncthreads();   // h1 ready

    // --- layer-2: 8 K-tiles, A ping-pong + 2-deep B prefetch ---
    auto loadA2 = [&](int t, hv8* dst) {
        #pragma unroll
        for (int mf = 0; mf < 4; ++mf)
            dst[mf] = *(const hv8*)(pb + swzH(mf * 16 + l15, (t << 5) | (kq << 3)));
    };
    hv8 av[2][4];
    loadA2(0, av[0]);
    #pragma unroll
    for (int t = 0; t < 8; ++t) {
        if (t + 1 < 8) loadA2(t + 1, av[(t + 1) & 1]);
        const hv8* avt = av[t & 1];
        const hv8* bvt = bv2[t & 1];
        __builtin_amdgcn_s_setprio(1);
        #pragma unroll
        for (int mf = 0; mf < 4; ++mf)
            #pragma unroll
            for (int nf = 0; nf < 4; ++nf)
                acc[mf][nf] = __builtin_amdgcn_mfma_f32_16x16x32_f16(avt[mf], bvt[nf], acc[mf][nf], 0, 0, 0);
        __builtin_amdgcn_s_setprio(0);
        if (t + 2 < 8) loadB2(t + 2, bv2[t & 1]);
    }

    // --- layer-3 B fragments (w3T[16][256]) ---
    hv8 bw3[8];
    #pragma unroll
    for (int t = 0; t < 8; ++t)
        bw3[t] = *(const hv8*)(w3T + l15 * 256 + ((t << 5) | (kq << 3)));

    __syncthreads();   // all layer-2 A-reads done
    // --- h2 = relu(acc) -> pb ---
    #pragma unroll
    for (int mf = 0; mf < 4; ++mf)
        #pragma unroll
        for (int nf = 0; nf < 4; ++nf) {
            const int col = nbase + nf * 16 + l15;
            const int r0 = mf * 16 + (kq << 2);
            #pragma unroll
            for (int r = 0; r < 4; ++r)
                pb[swzH(r0 + r, col)] = (_Float16)fmaxf(acc[mf][nf][r], 0.0f);
        }
    __syncthreads();

    // --- layer-3 MFMA: wave wv handles pixel rows [wv*16, wv*16+16) ---
    f32x4 acc3 = (f32x4){0.f, 0.f, 0.f, 0.f};
    #pragma unroll
    for (int t = 0; t < 8; ++t) {
        const hv8 av3 = *(const hv8*)(pb + swzH((wv << 4) + l15, (t << 5) | (kq << 3)));
        acc3 = __builtin_amdgcn_mfma_f32_16x16x32_f16(av3, bw3[t], acc3, 0, 0, 0);
    }
    if (l15 < 4) {
        const int ch = l15;
        #pragma unroll
        for (int r = 0; r < 4; ++r) {
            const int p = (wv << 4) + (kq << 2) + r;
            const int n = n0 + p;
            const bool m = pix[n] > 0;
            float v;
            if (ch == 3) v = m ? 1.0f : 0.0f;
            else         v = m ? (fmaxf(acc3[r] + b3[ch], 0.0f) - 1.0f)
                               : color_bg[(n >> 16) * 3 + ch];
            out[(size_t)n * 4 + ch] = v;
        }
    }
}

extern "C" void kernel_launch(void* const* d_in, const int* in_sizes, int n_in,
                              void* d_out, int out_size, void* d_ws, size_t ws_size,
                              hipStream_t stream) {
    const int*   pix      = (const int*)  d_in[0];
    const float* bary     = (const float*)d_in[1];
    const int*   faces    = (const int*)  d_in[2];
    const float* feature  = (const float*)d_in[3];
    const float* shapef   = (const float*)d_in[4];
    const float* color_bg = (const float*)d_in[5];
    const float* style    = (const float*)d_in[6];
    const float* w1       = (const float*)d_in[7];
    const float* b1       = (const float*)d_in[8];
    const float* w2       = (const float*)d_in[9];
    const float* b2       = (const float*)d_in[10];
    const float* w3       = (const float*)d_in[11];
    const float* b3       = (const float*)d_in[12];
    float* out = (float*)d_out;

    const int nV = in_sizes[3] / 256;                         // 50000 vertices

    char* ws = (char*)d_ws;
    _Float16* w1T  = (_Float16*)ws;                           // 229,376 B
    _Float16* w2T  = (_Float16*)(ws + 229376);                // 131,072 B
    float*    b1p  = (float*)   (ws + 360448);                // 1,024 B
    _Float16* w3T  = (_Float16*)(ws + 361472);                // 8,192 B
    _Float16* Ptab = (_Float16*)(ws + 369664);                // nV*256*2 = 25.6 MB

    hipLaunchKernelGGL(prep_weights, dim3(513), dim3(256), 0, stream,
                       style, w1, b1, w2, w3, w1T, w2T, w3T, b1p);
    hipLaunchKernelGGL(pgemm, dim3((nV + 63) / 64), dim3(256), 0, stream,
                       feature, shapef, w1T, Ptab, nV);

    const int npix = in_sizes[0];                             // 262144
    hipLaunchKernelGGL(renderer, dim3(npix / TILE_M), dim3(256), 0, stream,
                       pix, bary, faces, Ptab, color_bg,
                       b2, b3, w1T, w2T, w3T, b1p, out);
}

// Round 10
// 232.072 us; speedup vs baseline: 1.2005x; 1.0057x over previous
//
#include <hip/hip_runtime.h>
#include <math.h>

// DifferentiableMultiMLPRenderer — round 10: spill-window repair at 3 blocks/CU.
// P[v] = (feat[v]@W1a + shape[v]@W1b)/3 precomputed (pgemm). Pixel kernel:
// layer1 = blend(3 P-rows) + emb@W1e (K=64) + b1'; layer2 MFMA; layer3 MFMA.
// launch_bounds(256,3): unified 168/wave = 84 arch + 84 acc. Arch windows kept
// <= ~80: bw3 moved after h2-write (was 96-reg window); layer-1 ave/bve
// single-buffered (was 64-reg window). Gather: 8 batches x 8 px, 2-deep ping-pong.

typedef _Float16 hv8 __attribute__((ext_vector_type(8)));
typedef __attribute__((ext_vector_type(4))) float f32x4;

#define TILE_M 64

__device__ inline int swzE(int row, int k) { return row * 64  + (k ^ ((row & 7) << 3)); }
__device__ inline int swzH(int row, int k) { return row * 256 + (k ^ ((row & 7) << 3)); }
__device__ inline int swzA(int row, int k) { return row * 384 + (k ^ ((row & 7) << 3)); }

// ---- prep: fold style into b1; build f16 weights: w1T (1/3 folded), w2T, w3T ----
__global__ __launch_bounds__(256)
void prep_weights(const float* __restrict__ style,
                  const float* __restrict__ w1, const float* __restrict__ b1,
                  const float* __restrict__ w2, const float* __restrict__ w3,
                  _Float16* __restrict__ w1T, _Float16* __restrict__ w2T,
                  _Float16* __restrict__ w3T, float* __restrict__ b1p)
{
    const int j = blockIdx.x;
    const int t = threadIdx.x;
    if (j < 256) {
        float part = style[t] * w1[(size_t)(447 + t) * 256 + j];
        #pragma unroll
        for (int off = 32; off; off >>= 1) part += __shfl_down(part, off, 64);
        __shared__ float red[4];
        if ((t & 63) == 0) red[t >> 6] = part;
        __syncthreads();
        if (t == 0) b1p[j] = b1[j] + red[0] + red[1] + red[2] + red[3];
        for (int k = t; k < 448; k += 256) {
            float v = (k < 447) ? w1[(size_t)k * 256 + j] : 0.0f;
            if (k < 384) v *= (1.0f / 3.0f);
            w1T[(size_t)j * 448 + k] = (_Float16)v;
        }
    } else if (j < 512) {
        const int jj = j - 256;
        w2T[(size_t)jj * 256 + t] = (_Float16)w2[(size_t)t * 256 + jj];
    } else {
        #pragma unroll
        for (int r = 0; r < 16; ++r)
            w3T[r * 256 + t] = (r < 3) ? (_Float16)w3[t * 3 + r] : (_Float16)0.0f;
    }
}

// ---- pgemm: P[v][j] = sum_k [feat|shape][v][k] * w1T[j][k] (1/3 folded) ----
__global__ __launch_bounds__(256, 2)
void pgemm(const float* __restrict__ feat, const float* __restrict__ shp,
           const _Float16* __restrict__ w1T, _Float16* __restrict__ P, int nV)
{
    __shared__ _Float16 as[64 * 384];   // 48 KB
    const int tid = threadIdx.x;
    const int n0 = blockIdx.x * 64;
    const int lane = tid & 63, wv = tid >> 6;
    const int nbase = wv << 6, l15 = lane & 15, kq = lane >> 4;

    const hv8* bp[4];
    #pragma unroll
    for (int nf = 0; nf < 4; ++nf)
        bp[nf] = (const hv8*)(w1T + (size_t)(nbase + nf * 16 + l15) * 448 + (kq << 3));
    hv8 bv[3][4];
    auto loadB = [&](int t, hv8* dst) {
        #pragma unroll
        for (int nf = 0; nf < 4; ++nf) dst[nf] = bp[nf][t << 2];
    };
    loadB(0, bv[0]); loadB(1, bv[1]); loadB(2, bv[2]);

    #pragma unroll
    for (int i = 0; i < 12; ++i) {
        const int id = tid + i * 256;
        const int row = id / 48;
        const int g = id - row * 48;
        int v = n0 + row; if (v >= nV) v = nV - 1;
        const float* s = (g < 32) ? (feat + (size_t)v * 256 + g * 8)
                                  : (shp  + (size_t)v * 128 + (g - 32) * 8);
        const float4 a = ((const float4*)s)[0];
        const float4 b = ((const float4*)s)[1];
        hv8 h = { (_Float16)a.x, (_Float16)a.y, (_Float16)a.z, (_Float16)a.w,
                  (_Float16)b.x, (_Float16)b.y, (_Float16)b.z, (_Float16)b.w };
        *(hv8*)(&as[swzA(row, g * 8)]) = h;
    }
    f32x4 acc[4][4];
    #pragma unroll
    for (int mf = 0; mf < 4; ++mf)
        #pragma unroll
        for (int nf = 0; nf < 4; ++nf) acc[mf][nf] = (f32x4){0.f, 0.f, 0.f, 0.f};
    __syncthreads();

    auto loadA = [&](int t, hv8* dst) {
        #pragma unroll
        for (int mf = 0; mf < 4; ++mf)
            dst[mf] = *(const hv8*)(as + swzA(mf * 16 + l15, (t << 5) | (kq << 3)));
    };
    hv8 av[2][4];
    loadA(0, av[0]);
    #pragma unroll
    for (int t = 0; t < 12; ++t) {
        if (t + 1 < 12) loadA(t + 1, av[(t + 1) & 1]);
        const hv8* avt = av[t & 1];
        const hv8* bvt = bv[t % 3];
        __builtin_amdgcn_s_setprio(1);
        #pragma unroll
        for (int mf = 0; mf < 4; ++mf)
            #pragma unroll
            for (int nf = 0; nf < 4; ++nf)
                acc[mf][nf] = __builtin_amdgcn_mfma_f32_16x16x32_f16(avt[mf], bvt[nf], acc[mf][nf], 0, 0, 0);
        __builtin_amdgcn_s_setprio(0);
        if (t + 3 < 12) loadB(t + 3, bv[t % 3]);
    }
    #pragma unroll
    for (int mf = 0; mf < 4; ++mf)
        #pragma unroll
        for (int nf = 0; nf < 4; ++nf) {
            const int col = nbase + nf * 16 + l15;
            const int r0 = mf * 16 + (kq << 2);
            #pragma unroll
            for (int r = 0; r < 4; ++r) {
                const int v = n0 + r0 + r;
                if (v < nV) P[(size_t)v * 256 + col] = (_Float16)acc[mf][nf][r];
            }
        }
}

// ---- main fused pixel kernel ----
__global__ __launch_bounds__(256, 3)
void renderer(const int* __restrict__ pix, const float* __restrict__ bary,
              const int* __restrict__ faces,
              const _Float16* __restrict__ P,
              const float* __restrict__ color_bg,
              const float* __restrict__ b2g,
              const float* __restrict__ b3,
              const _Float16* __restrict__ w1T,
              const _Float16* __restrict__ w2T,
              const _Float16* __restrict__ w3T,
              const float* __restrict__ b1p,
              float* __restrict__ out)
{
    __shared__ _Float16 embs[64 * 64];    // 8 KB
    __shared__ _Float16 pb[64 * 256];     // 32 KB: blend -> h1 (in-place) -> h2
    __shared__ int   vidx[TILE_M][3];
    __shared__ float bcs[TILE_M][3];

    const int tid = threadIdx.x;
    const int cpx = gridDim.x >> 3;
    const int bid = (blockIdx.x & 7) * cpx + (blockIdx.x >> 3);   // XCD-aware
    const int n0  = bid * TILE_M;

    const int lane  = tid & 63;
    const int wv    = tid >> 6;
    const int nbase = wv << 6;
    const int l15   = lane & 15;
    const int kq    = lane >> 4;

    if (tid < TILE_M) {
        const int n = n0 + tid;
        const int face = pix[n];
        vidx[tid][0] = faces[face * 3 + 0];
        vidx[tid][1] = faces[face * 3 + 1];
        vidx[tid][2] = faces[face * 3 + 2];
        bcs[tid][0] = bary[n * 3 + 0];
        bcs[tid][1] = bary[n * 3 + 1];
        bcs[tid][2] = bary[n * 3 + 2];
    }
    __syncthreads();

    const int gp = tid >> 5;            // 0..7 : pixel within batch
    const int c8 = (tid & 31) << 3;     // col chunk (32 lanes cover a 512B row)

    // gather: 8 batches x 8 px; 2-deep ping-pong, 24 VGPR per slot (48 peak)
    hv8 g0[3], g1[3];
    auto loadG = [&](hv8* g, const int b) {
        const int p = b * 8 + gp;
        g[0] = *(const hv8*)(P + (size_t)vidx[p][0] * 256 + c8);
        g[1] = *(const hv8*)(P + (size_t)vidx[p][1] * 256 + c8);
        g[2] = *(const hv8*)(P + (size_t)vidx[p][2] * 256 + c8);
    };
    auto blendG = [&](hv8* g, const int b) {
        const int p = b * 8 + gp;
        const _Float16 c0 = (_Float16)bcs[p][0];
        const _Float16 c1 = (_Float16)bcs[p][1];
        const _Float16 c2 = (_Float16)bcs[p][2];
        *(hv8*)(&pb[swzH(p, c8)]) = g[0] * c0 + g[1] * c1 + g[2] * c2;
    };

    loadG(g0, 0);
    loadG(g1, 1);

    // --- emb (NeRF embed of bary) -> embs; VALU hides batch-0/1 gather latency ---
    {
        const int p = tid >> 2;
        const int e16 = (tid & 3) << 4;
        const float c0 = bcs[p][0], c1 = bcs[p][1], c2 = bcs[p][2];
        #pragma unroll
        for (int hh = 0; hh < 2; ++hh) {
            hv8 h;
            #pragma unroll
            for (int i = 0; i < 8; ++i) {
                const int s = e16 + hh * 8 + i;
                float v;
                if (s < 3) v = (s == 0) ? c0 : ((s == 1) ? c1 : c2);
                else if (s < 63) {
                    const int q = s - 3;
                    const int f = q / 6;
                    const int rem = q - f * 6;
                    const int d = (rem >= 3) ? rem - 3 : rem;
                    const float bd = (d == 0) ? c0 : ((d == 1) ? c1 : c2);
                    const float arg = bd * (float)(1 << f);
                    v = (rem < 3) ? __sinf(arg) : __cosf(arg);
                } else v = 0.0f;
                h[i] = (_Float16)v;
            }
            *(hv8*)(&embs[swzE(p, e16 + hh * 8)]) = h;
        }
    }

    // drain the pipeline: blend b, immediately re-issue b+2 into the freed slot
    blendG(g0, 0); loadG(g0, 2);
    blendG(g1, 1); loadG(g1, 3);
    blendG(g0, 2); loadG(g0, 4);
    blendG(g1, 3); loadG(g1, 5);
    blendG(g0, 4); loadG(g0, 6);
    blendG(g1, 5); loadG(g1, 7);
    blendG(g0, 6);
    blendG(g1, 7);

    f32x4 acc[4][4];
    #pragma unroll
    for (int nf = 0; nf < 4; ++nf) {
        const float b = b1p[nbase + nf * 16 + l15];
        #pragma unroll
        for (int mf = 0; mf < 4; ++mf) acc[mf][nf] = (f32x4){b, b, b, b};
    }
    __syncthreads();   // embs + pb(blend) ready

    // --- layer-1 emb MFMA (2 tiles, single-buffered frags: 32-reg window) ---
    #pragma unroll
    for (int t = 0; t < 2; ++t) {
        hv8 ave[4], bve[4];
        #pragma unroll
        for (int nf = 0; nf < 4; ++nf)
            bve[nf] = *(const hv8*)(w1T + (size_t)(nbase + nf * 16 + l15) * 448 + 384 + (t << 5) + (kq << 3));
        #pragma unroll
        for (int mf = 0; mf < 4; ++mf)
            ave[mf] = *(const hv8*)(embs + swzE(mf * 16 + l15, (t << 5) | (kq << 3)));
        __builtin_amdgcn_s_setprio(1);
        #pragma unroll
        for (int mf = 0; mf < 4; ++mf)
            #pragma unroll
            for (int nf = 0; nf < 4; ++nf)
                acc[mf][nf] = __builtin_amdgcn_mfma_f32_16x16x32_f16(ave[mf], bve[nf], acc[mf][nf], 0, 0, 0);
        __builtin_amdgcn_s_setprio(0);
    }

    // --- layer-2 B prefetch (depth 2) ---
    const hv8* bp2[4];
    #pragma unroll
    for (int nf = 0; nf < 4; ++nf)
        bp2[nf] = (const hv8*)(w2T + (size_t)(nbase + nf * 16 + l15) * 256 + (kq << 3));
    hv8 bv2[2][4];
    auto loadB2 = [&](int t, hv8* dst) {
        #pragma unroll
        for (int nf = 0; nf < 4; ++nf) dst[nf] = bp2[nf][t << 2];
    };
    loadB2(0, bv2[0]); loadB2(1, bv2[1]);

    // --- layer-1 epilogue: h1 = relu(acc + pb) IN-PLACE; acc = b2 ---
    #pragma unroll
    for (int mf = 0; mf < 4; ++mf)
        #pragma unroll
        for (int nf = 0; nf < 4; ++nf) {
            const int col = nbase + nf * 16 + l15;
            const int r0 = mf * 16 + (kq << 2);
            #pragma unroll
            for (int r = 0; r < 4; ++r) {
                const int sl = swzH(r0 + r, col);
                const float pv = (float)pb[sl];
                pb[sl] = (_Float16)fmaxf(acc[mf][nf][r] + pv, 0.0f);
            }
            const float b = b2g[col];
            acc[mf][nf] = (f32x4){b, b, b, b};
        }
    __syncthreads();   // h1 ready

    // --- layer-2: 8 K-tiles, A ping-pong + 2-deep B prefetch ---
    auto loadA2 = [&](int t, hv8* dst) {
        #pragma unroll
        for (int mf = 0; mf < 4; ++mf)
            dst[mf] = *(const hv8*)(pb + swzH(mf * 16 + l15, (t << 5) | (kq << 3)));
    };
    hv8 av[2][4];
    loadA2(0, av[0]);
    #pragma unroll
    for (int t = 0; t < 8; ++t) {
        if (t + 1 < 8) loadA2(t + 1, av[(t + 1) & 1]);
        const hv8* avt = av[t & 1];
        const hv8* bvt = bv2[t & 1];
        __builtin_amdgcn_s_setprio(1);
        #pragma unroll
        for (int mf = 0; mf < 4; ++mf)
            #pragma unroll
            for (int nf = 0; nf < 4; ++nf)
                acc[mf][nf] = __builtin_amdgcn_mfma_f32_16x16x32_f16(avt[mf], bvt[nf], acc[mf][nf], 0, 0, 0);
        __builtin_amdgcn_s_setprio(0);
        if (t + 2 < 8) loadB2(t + 2, bv2[t & 1]);
    }

    __syncthreads();   // all layer-2 A-reads done
    // --- h2 = relu(acc) -> pb ---
    #pragma unroll
    for (int mf = 0; mf < 4; ++mf)
        #pragma unroll
        for (int nf = 0; nf < 4; ++nf) {
            const int col = nbase + nf * 16 + l15;
            const int r0 = mf * 16 + (kq << 2);
            #pragma unroll
            for (int r = 0; r < 4; ++r)
                pb[swzH(r0 + r, col)] = (_Float16)fmaxf(acc[mf][nf][r], 0.0f);
        }

    // --- layer-3 B fragments (w3T[16][256]); acc dead -> ~40-reg window;
    //     L2 latency hides under the barrier wait ---
    hv8 bw3[8];
    #pragma unroll
    for (int t = 0; t < 8; ++t)
        bw3[t] = *(const hv8*)(w3T + l15 * 256 + ((t << 5) | (kq << 3)));
    __syncthreads();

    // --- layer-3 MFMA: wave wv handles pixel rows [wv*16, wv*16+16) ---
    f32x4 acc3 = (f32x4){0.f, 0.f, 0.f, 0.f};
    #pragma unroll
    for (int t = 0; t < 8; ++t) {
        const hv8 av3 = *(const hv8*)(pb + swzH((wv << 4) + l15, (t << 5) | (kq << 3)));
        acc3 = __builtin_amdgcn_mfma_f32_16x16x32_f16(av3, bw3[t], acc3, 0, 0, 0);
    }
    if (l15 < 4) {
        const int ch = l15;
        #pragma unroll
        for (int r = 0; r < 4; ++r) {
            const int p = (wv << 4) + (kq << 2) + r;
            const int n = n0 + p;
            const bool m = pix[n] > 0;
            float v;
            if (ch == 3) v = m ? 1.0f : 0.0f;
            else         v = m ? (fmaxf(acc3[r] + b3[ch], 0.0f) - 1.0f)
                               : color_bg[(n >> 16) * 3 + ch];
            out[(size_t)n * 4 + ch] = v;
        }
    }
}

extern "C" void kernel_launch(void* const* d_in, const int* in_sizes, int n_in,
                              void* d_out, int out_size, void* d_ws, size_t ws_size,
                              hipStream_t stream) {
    const int*   pix      = (const int*)  d_in[0];
    const float* bary     = (const float*)d_in[1];
    const int*   faces    = (const int*)  d_in[2];
    const float* feature  = (const float*)d_in[3];
    const float* shapef   = (const float*)d_in[4];
    const float* color_bg = (const float*)d_in[5];
    const float* style    = (const float*)d_in[6];
    const float* w1       = (const float*)d_in[7];
    const float* b1       = (const float*)d_in[8];
    const float* w2       = (const float*)d_in[9];
    const float* b2       = (const float*)d_in[10];
    const float* w3       = (const float*)d_in[11];
    const float* b3       = (const float*)d_in[12];
    float* out = (float*)d_out;

    const int nV = in_sizes[3] / 256;                         // 50000 vertices

    char* ws = (char*)d_ws;
    _Float16* w1T  = (_Float16*)ws;                           // 229,376 B
    _Float16* w2T  = (_Float16*)(ws + 229376);                // 131,072 B
    float*    b1p  = (float*)   (ws + 360448);                // 1,024 B
    _Float16* w3T  = (_Float16*)(ws + 361472);                // 8,192 B
    _Float16* Ptab = (_Float16*)(ws + 369664);                // nV*256*2 = 25.6 MB

    hipLaunchKernelGGL(prep_weights, dim3(513), dim3(256), 0, stream,
                       style, w1, b1, w2, w3, w1T, w2T, w3T, b1p);
    hipLaunchKernelGGL(pgemm, dim3((nV + 63) / 64), dim3(256), 0, stream,
                       feature, shapef, w1T, Ptab, nV);

    const int npix = in_sizes[0];                             // 262144
    hipLaunchKernelGGL(renderer, dim3(npix / TILE_M), dim3(256), 0, stream,
                       pix, bary, faces, Ptab, color_bg,
                       b2, b3, w1T, w2T, w3T, b1p, out);
}

// Round 11
// 202.540 us; speedup vs baseline: 1.3755x; 1.1458x over previous
//
#include <hip/hip_runtime.h>
#include <math.h>

// DifferentiableMultiMLPRenderer — round 11: spill elimination via (256,2).
// r7-r10 lesson: at launch_bounds(256,3) the 84-arch budget forces ~42KB/block
// scratch traffic (172MB WRITE) that tracks duration 1:1. Revert to (256,2)
// (proven spill-free) and drop manual layer-2 pipelining — compiler schedules
// ds_read/MFMA fine with register headroom. Structure otherwise = r10.

typedef _Float16 hv8 __attribute__((ext_vector_type(8)));
typedef __attribute__((ext_vector_type(4))) float f32x4;

#define TILE_M 64

__device__ inline int swzE(int row, int k) { return row * 64  + (k ^ ((row & 7) << 3)); }
__device__ inline int swzH(int row, int k) { return row * 256 + (k ^ ((row & 7) << 3)); }
__device__ inline int swzA(int row, int k) { return row * 384 + (k ^ ((row & 7) << 3)); }

// ---- prep: fold style into b1; build f16 weights: w1T (1/3 folded), w2T, w3T ----
__global__ __launch_bounds__(256)
void prep_weights(const float* __restrict__ style,
                  const float* __restrict__ w1, const float* __restrict__ b1,
                  const float* __restrict__ w2, const float* __restrict__ w3,
                  _Float16* __restrict__ w1T, _Float16* __restrict__ w2T,
                  _Float16* __restrict__ w3T, float* __restrict__ b1p)
{
    const int j = blockIdx.x;
    const int t = threadIdx.x;
    if (j < 256) {
        float part = style[t] * w1[(size_t)(447 + t) * 256 + j];
        #pragma unroll
        for (int off = 32; off; off >>= 1) part += __shfl_down(part, off, 64);
        __shared__ float red[4];
        if ((t & 63) == 0) red[t >> 6] = part;
        __syncthreads();
        if (t == 0) b1p[j] = b1[j] + red[0] + red[1] + red[2] + red[3];
        for (int k = t; k < 448; k += 256) {
            float v = (k < 447) ? w1[(size_t)k * 256 + j] : 0.0f;
            if (k < 384) v *= (1.0f / 3.0f);
            w1T[(size_t)j * 448 + k] = (_Float16)v;
        }
    } else if (j < 512) {
        const int jj = j - 256;
        w2T[(size_t)jj * 256 + t] = (_Float16)w2[(size_t)t * 256 + jj];
    } else {
        #pragma unroll
        for (int r = 0; r < 16; ++r)
            w3T[r * 256 + t] = (r < 3) ? (_Float16)w3[t * 3 + r] : (_Float16)0.0f;
    }
}

// ---- pgemm: P[v][j] = sum_k [feat|shape][v][k] * w1T[j][k] (1/3 folded) ----
__global__ __launch_bounds__(256, 2)
void pgemm(const float* __restrict__ feat, const float* __restrict__ shp,
           const _Float16* __restrict__ w1T, _Float16* __restrict__ P, int nV)
{
    __shared__ _Float16 as[64 * 384];   // 48 KB
    const int tid = threadIdx.x;
    const int n0 = blockIdx.x * 64;
    const int lane = tid & 63, wv = tid >> 6;
    const int nbase = wv << 6, l15 = lane & 15, kq = lane >> 4;

    const hv8* bp[4];
    #pragma unroll
    for (int nf = 0; nf < 4; ++nf)
        bp[nf] = (const hv8*)(w1T + (size_t)(nbase + nf * 16 + l15) * 448 + (kq << 3));
    hv8 bv[3][4];
    auto loadB = [&](int t, hv8* dst) {
        #pragma unroll
        for (int nf = 0; nf < 4; ++nf) dst[nf] = bp[nf][t << 2];
    };
    loadB(0, bv[0]); loadB(1, bv[1]); loadB(2, bv[2]);

    #pragma unroll
    for (int i = 0; i < 12; ++i) {
        const int id = tid + i * 256;
        const int row = id / 48;
        const int g = id - row * 48;
        int v = n0 + row; if (v >= nV) v = nV - 1;
        const float* s = (g < 32) ? (feat + (size_t)v * 256 + g * 8)
                                  : (shp  + (size_t)v * 128 + (g - 32) * 8);
        const float4 a = ((const float4*)s)[0];
        const float4 b = ((const float4*)s)[1];
        hv8 h = { (_Float16)a.x, (_Float16)a.y, (_Float16)a.z, (_Float16)a.w,
                  (_Float16)b.x, (_Float16)b.y, (_Float16)b.z, (_Float16)b.w };
        *(hv8*)(&as[swzA(row, g * 8)]) = h;
    }
    f32x4 acc[4][4];
    #pragma unroll
    for (int mf = 0; mf < 4; ++mf)
        #pragma unroll
        for (int nf = 0; nf < 4; ++nf) acc[mf][nf] = (f32x4){0.f, 0.f, 0.f, 0.f};
    __syncthreads();

    auto loadA = [&](int t, hv8* dst) {
        #pragma unroll
        for (int mf = 0; mf < 4; ++mf)
            dst[mf] = *(const hv8*)(as + swzA(mf * 16 + l15, (t << 5) | (kq << 3)));
    };
    hv8 av[2][4];
    loadA(0, av[0]);
    #pragma unroll
    for (int t = 0; t < 12; ++t) {
        if (t + 1 < 12) loadA(t + 1, av[(t + 1) & 1]);
        const hv8* avt = av[t & 1];
        const hv8* bvt = bv[t % 3];
        __builtin_amdgcn_s_setprio(1);
        #pragma unroll
        for (int mf = 0; mf < 4; ++mf)
            #pragma unroll
            for (int nf = 0; nf < 4; ++nf)
                acc[mf][nf] = __builtin_amdgcn_mfma_f32_16x16x32_f16(avt[mf], bvt[nf], acc[mf][nf], 0, 0, 0);
        __builtin_amdgcn_s_setprio(0);
        if (t + 3 < 12) loadB(t + 3, bv[t % 3]);
    }
    #pragma unroll
    for (int mf = 0; mf < 4; ++mf)
        #pragma unroll
        for (int nf = 0; nf < 4; ++nf) {
            const int col = nbase + nf * 16 + l15;
            const int r0 = mf * 16 + (kq << 2);
            #pragma unroll
            for (int r = 0; r < 4; ++r) {
                const int v = n0 + r0 + r;
                if (v < nV) P[(size_t)v * 256 + col] = (_Float16)acc[mf][nf][r];
            }
        }
}

// ---- main fused pixel kernel ----
__global__ __launch_bounds__(256, 2)
void renderer(const int* __restrict__ pix, const float* __restrict__ bary,
              const int* __restrict__ faces,
              const _Float16* __restrict__ P,
              const float* __restrict__ color_bg,
              const float* __restrict__ b2g,
              const float* __restrict__ b3,
              const _Float16* __restrict__ w1T,
              const _Float16* __restrict__ w2T,
              const _Float16* __restrict__ w3T,
              const float* __restrict__ b1p,
              float* __restrict__ out)
{
    __shared__ _Float16 embs[64 * 64];    // 8 KB
    __shared__ _Float16 pb[64 * 256];     // 32 KB: blend -> h1 (in-place) -> h2
    __shared__ int   vidx[TILE_M][3];
    __shared__ float bcs[TILE_M][3];

    const int tid = threadIdx.x;
    const int cpx = gridDim.x >> 3;
    const int bid = (blockIdx.x & 7) * cpx + (blockIdx.x >> 3);   // XCD-aware
    const int n0  = bid * TILE_M;

    const int lane  = tid & 63;
    const int wv    = tid >> 6;
    const int nbase = wv << 6;
    const int l15   = lane & 15;
    const int kq    = lane >> 4;

    if (tid < TILE_M) {
        const int n = n0 + tid;
        const int face = pix[n];
        vidx[tid][0] = faces[face * 3 + 0];
        vidx[tid][1] = faces[face * 3 + 1];
        vidx[tid][2] = faces[face * 3 + 2];
        bcs[tid][0] = bary[n * 3 + 0];
        bcs[tid][1] = bary[n * 3 + 1];
        bcs[tid][2] = bary[n * 3 + 2];
    }
    __syncthreads();

    const int gp = tid >> 5;            // 0..7 : pixel within batch
    const int c8 = (tid & 31) << 3;     // col chunk (32 lanes cover a 512B row)

    // gather: 8 batches x 8 px; 2-deep ping-pong (T14 issue-early/consume-late)
    hv8 g0[3], g1[3];
    auto loadG = [&](hv8* g, const int b) {
        const int p = b * 8 + gp;
        g[0] = *(const hv8*)(P + (size_t)vidx[p][0] * 256 + c8);
        g[1] = *(const hv8*)(P + (size_t)vidx[p][1] * 256 + c8);
        g[2] = *(const hv8*)(P + (size_t)vidx[p][2] * 256 + c8);
    };
    auto blendG = [&](hv8* g, const int b) {
        const int p = b * 8 + gp;
        const _Float16 c0 = (_Float16)bcs[p][0];
        const _Float16 c1 = (_Float16)bcs[p][1];
        const _Float16 c2 = (_Float16)bcs[p][2];
        *(hv8*)(&pb[swzH(p, c8)]) = g[0] * c0 + g[1] * c1 + g[2] * c2;
    };

    loadG(g0, 0);
    loadG(g1, 1);

    // --- emb (NeRF embed of bary) -> embs; VALU hides batch-0/1 gather latency ---
    {
        const int p = tid >> 2;
        const int e16 = (tid & 3) << 4;
        const float c0 = bcs[p][0], c1 = bcs[p][1], c2 = bcs[p][2];
        #pragma unroll
        for (int hh = 0; hh < 2; ++hh) {
            hv8 h;
            #pragma unroll
            for (int i = 0; i < 8; ++i) {
                const int s = e16 + hh * 8 + i;
                float v;
                if (s < 3) v = (s == 0) ? c0 : ((s == 1) ? c1 : c2);
                else if (s < 63) {
                    const int q = s - 3;
                    const int f = q / 6;
                    const int rem = q - f * 6;
                    const int d = (rem >= 3) ? rem - 3 : rem;
                    const float bd = (d == 0) ? c0 : ((d == 1) ? c1 : c2);
                    const float arg = bd * (float)(1 << f);
                    v = (rem < 3) ? __sinf(arg) : __cosf(arg);
                } else v = 0.0f;
                h[i] = (_Float16)v;
            }
            *(hv8*)(&embs[swzE(p, e16 + hh * 8)]) = h;
        }
    }

    // drain the pipeline: blend b, immediately re-issue b+2 into the freed slot
    blendG(g0, 0); loadG(g0, 2);
    blendG(g1, 1); loadG(g1, 3);
    blendG(g0, 2); loadG(g0, 4);
    blendG(g1, 3); loadG(g1, 5);
    blendG(g0, 4); loadG(g0, 6);
    blendG(g1, 5); loadG(g1, 7);
    blendG(g0, 6);
    blendG(g1, 7);

    f32x4 acc[4][4];
    #pragma unroll
    for (int nf = 0; nf < 4; ++nf) {
        const float b = b1p[nbase + nf * 16 + l15];
        #pragma unroll
        for (int mf = 0; mf < 4; ++mf) acc[mf][nf] = (f32x4){b, b, b, b};
    }
    __syncthreads();   // embs + pb(blend) ready

    // --- layer-1 emb MFMA (2 tiles) ---
    #pragma unroll
    for (int t = 0; t < 2; ++t) {
        hv8 ave[4], bve[4];
        #pragma unroll
        for (int nf = 0; nf < 4; ++nf)
            bve[nf] = *(const hv8*)(w1T + (size_t)(nbase + nf * 16 + l15) * 448 + 384 + (t << 5) + (kq << 3));
        #pragma unroll
        for (int mf = 0; mf < 4; ++mf)
            ave[mf] = *(const hv8*)(embs + swzE(mf * 16 + l15, (t << 5) | (kq << 3)));
        __builtin_amdgcn_s_setprio(1);
        #pragma unroll
        for (int mf = 0; mf < 4; ++mf)
            #pragma unroll
            for (int nf = 0; nf < 4; ++nf)
                acc[mf][nf] = __builtin_amdgcn_mfma_f32_16x16x32_f16(ave[mf], bve[nf], acc[mf][nf], 0, 0, 0);
        __builtin_amdgcn_s_setprio(0);
    }

    // --- layer-1 epilogue: h1 = relu(acc + pb) IN-PLACE; acc = b2 ---
    #pragma unroll
    for (int mf = 0; mf < 4; ++mf)
        #pragma unroll
        for (int nf = 0; nf < 4; ++nf) {
            const int col = nbase + nf * 16 + l15;
            const int r0 = mf * 16 + (kq << 2);
            #pragma unroll
            for (int r = 0; r < 4; ++r) {
                const int sl = swzH(r0 + r, col);
                const float pv = (float)pb[sl];
                pb[sl] = (_Float16)fmaxf(acc[mf][nf][r] + pv, 0.0f);
            }
            const float b = b2g[col];
            acc[mf][nf] = (f32x4){b, b, b, b};
        }
    __syncthreads();   // h1 ready

    // --- layer-2: 8 K-tiles; per-tile fragment loads, compiler-scheduled ---
    const hv8* bp2[4];
    #pragma unroll
    for (int nf = 0; nf < 4; ++nf)
        bp2[nf] = (const hv8*)(w2T + (size_t)(nbase + nf * 16 + l15) * 256 + (kq << 3));
    #pragma unroll
    for (int t = 0; t < 8; ++t) {
        hv8 av[4], bv[4];
        #pragma unroll
        for (int nf = 0; nf < 4; ++nf) bv[nf] = bp2[nf][t << 2];
        #pragma unroll
        for (int mf = 0; mf < 4; ++mf)
            av[mf] = *(const hv8*)(pb + swzH(mf * 16 + l15, (t << 5) | (kq << 3)));
        __builtin_amdgcn_s_setprio(1);
        #pragma unroll
        for (int mf = 0; mf < 4; ++mf)
            #pragma unroll
            for (int nf = 0; nf < 4; ++nf)
                acc[mf][nf] = __builtin_amdgcn_mfma_f32_16x16x32_f16(av[mf], bv[nf], acc[mf][nf], 0, 0, 0);
        __builtin_amdgcn_s_setprio(0);
    }

    __syncthreads();   // all layer-2 A-reads done
    // --- h2 = relu(acc) -> pb ---
    #pragma unroll
    for (int mf = 0; mf < 4; ++mf)
        #pragma unroll
        for (int nf = 0; nf < 4; ++nf) {
            const int col = nbase + nf * 16 + l15;
            const int r0 = mf * 16 + (kq << 2);
            #pragma unroll
            for (int r = 0; r < 4; ++r)
                pb[swzH(r0 + r, col)] = (_Float16)fmaxf(acc[mf][nf][r], 0.0f);
        }

    // --- layer-3 B fragments; L2 latency hides under the barrier wait ---
    hv8 bw3[8];
    #pragma unroll
    for (int t = 0; t < 8; ++t)
        bw3[t] = *(const hv8*)(w3T + l15 * 256 + ((t << 5) | (kq << 3)));
    __syncthreads();

    // --- layer-3 MFMA: wave wv handles pixel rows [wv*16, wv*16+16) ---
    f32x4 acc3 = (f32x4){0.f, 0.f, 0.f, 0.f};
    #pragma unroll
    for (int t = 0; t < 8; ++t) {
        const hv8 av3 = *(const hv8*)(pb + swzH((wv << 4) + l15, (t << 5) | (kq << 3)));
        acc3 = __builtin_amdgcn_mfma_f32_16x16x32_f16(av3, bw3[t], acc3, 0, 0, 0);
    }
    if (l15 < 4) {
        const int ch = l15;
        #pragma unroll
        for (int r = 0; r < 4; ++r) {
            const int p = (wv << 4) + (kq << 2) + r;
            const int n = n0 + p;
            const bool m = pix[n] > 0;
            float v;
            if (ch == 3) v = m ? 1.0f : 0.0f;
            else         v = m ? (fmaxf(acc3[r] + b3[ch], 0.0f) - 1.0f)
                               : color_bg[(n >> 16) * 3 + ch];
            out[(size_t)n * 4 + ch] = v;
        }
    }
}

extern "C" void kernel_launch(void* const* d_in, const int* in_sizes, int n_in,
                              void* d_out, int out_size, void* d_ws, size_t ws_size,
                              hipStream_t stream) {
    const int*   pix      = (const int*)  d_in[0];
    const float* bary     = (const float*)d_in[1];
    const int*   faces    = (const int*)  d_in[2];
    const float* feature  = (const float*)d_in[3];
    const float* shapef   = (const float*)d_in[4];
    const float* color_bg = (const float*)d_in[5];
    const float* style    = (const float*)d_in[6];
    const float* w1       = (const float*)d_in[7];
    const float* b1       = (const float*)d_in[8];
    const float* w2       = (const float*)d_in[9];
    const float* b2       = (const float*)d_in[10];
    const float* w3       = (const float*)d_in[11];
    const float* b3       = (const float*)d_in[12];
    float* out = (float*)d_out;

    const int nV = in_sizes[3] / 256;                         // 50000 vertices

    char* ws = (char*)d_ws;
    _Float16* w1T  = (_Float16*)ws;                           // 229,376 B
    _Float16* w2T  = (_Float16*)(ws + 229376);                // 131,072 B
    float*    b1p  = (float*)   (ws + 360448);                // 1,024 B
    _Float16* w3T  = (_Float16*)(ws + 361472);                // 8,192 B
    _Float16* Ptab = (_Float16*)(ws + 369664);                // nV*256*2 = 25.6 MB

    hipLaunchKernelGGL(prep_weights, dim3(513), dim3(256), 0, stream,
                       style, w1, b1, w2, w3, w1T, w2T, w3T, b1p);
    hipLaunchKernelGGL(pgemm, dim3((nV + 63) / 64), dim3(256), 0, stream,
                       feature, shapef, w1T, Ptab, nV);

    const int npix = in_sizes[0];                             // 262144
    hipLaunchKernelGGL(renderer, dim3(npix / TILE_M), dim3(256), 0, stream,
                       pix, bary, faces, Ptab, color_bg,
                       b2, b3, w1T, w2T, w3T, b1p, out);
}

// Round 12
// 185.730 us; speedup vs baseline: 1.5000x; 1.0905x over previous
//
#include <hip/hip_runtime.h>
#include <math.h>

// DifferentiableMultiMLPRenderer — round 12: r11 structure at 3 blocks/CU.
// r11 (simplified, spill-free) uses ~156 unified regs <= 168 budget of
// launch_bounds(256,3); r7-r10's spills came from the heavier pipelined body.
// Minimal diff vs r11: renderer bounds (256,2) -> (256,3). Verify via
// WRITE_SIZE (~4MB = fit; >=50MB = spill, direction dead).

typedef _Float16 hv8 __attribute__((ext_vector_type(8)));
typedef __attribute__((ext_vector_type(4))) float f32x4;

#define TILE_M 64

__device__ inline int swzE(int row, int k) { return row * 64  + (k ^ ((row & 7) << 3)); }
__device__ inline int swzH(int row, int k) { return row * 256 + (k ^ ((row & 7) << 3)); }
__device__ inline int swzA(int row, int k) { return row * 384 + (k ^ ((row & 7) << 3)); }

// ---- prep: fold style into b1; build f16 weights: w1T (1/3 folded), w2T, w3T ----
__global__ __launch_bounds__(256)
void prep_weights(const float* __restrict__ style,
                  const float* __restrict__ w1, const float* __restrict__ b1,
                  const float* __restrict__ w2, const float* __restrict__ w3,
                  _Float16* __restrict__ w1T, _Float16* __restrict__ w2T,
                  _Float16* __restrict__ w3T, float* __restrict__ b1p)
{
    const int j = blockIdx.x;
    const int t = threadIdx.x;
    if (j < 256) {
        float part = style[t] * w1[(size_t)(447 + t) * 256 + j];
        #pragma unroll
        for (int off = 32; off; off >>= 1) part += __shfl_down(part, off, 64);
        __shared__ float red[4];
        if ((t & 63) == 0) red[t >> 6] = part;
        __syncthreads();
        if (t == 0) b1p[j] = b1[j] + red[0] + red[1] + red[2] + red[3];
        for (int k = t; k < 448; k += 256) {
            float v = (k < 447) ? w1[(size_t)k * 256 + j] : 0.0f;
            if (k < 384) v *= (1.0f / 3.0f);
            w1T[(size_t)j * 448 + k] = (_Float16)v;
        }
    } else if (j < 512) {
        const int jj = j - 256;
        w2T[(size_t)jj * 256 + t] = (_Float16)w2[(size_t)t * 256 + jj];
    } else {
        #pragma unroll
        for (int r = 0; r < 16; ++r)
            w3T[r * 256 + t] = (r < 3) ? (_Float16)w3[t * 3 + r] : (_Float16)0.0f;
    }
}

// ---- pgemm: P[v][j] = sum_k [feat|shape][v][k] * w1T[j][k] (1/3 folded) ----
__global__ __launch_bounds__(256, 2)
void pgemm(const float* __restrict__ feat, const float* __restrict__ shp,
           const _Float16* __restrict__ w1T, _Float16* __restrict__ P, int nV)
{
    __shared__ _Float16 as[64 * 384];   // 48 KB
    const int tid = threadIdx.x;
    const int n0 = blockIdx.x * 64;
    const int lane = tid & 63, wv = tid >> 6;
    const int nbase = wv << 6, l15 = lane & 15, kq = lane >> 4;

    const hv8* bp[4];
    #pragma unroll
    for (int nf = 0; nf < 4; ++nf)
        bp[nf] = (const hv8*)(w1T + (size_t)(nbase + nf * 16 + l15) * 448 + (kq << 3));
    hv8 bv[3][4];
    auto loadB = [&](int t, hv8* dst) {
        #pragma unroll
        for (int nf = 0; nf < 4; ++nf) dst[nf] = bp[nf][t << 2];
    };
    loadB(0, bv[0]); loadB(1, bv[1]); loadB(2, bv[2]);

    #pragma unroll
    for (int i = 0; i < 12; ++i) {
        const int id = tid + i * 256;
        const int row = id / 48;
        const int g = id - row * 48;
        int v = n0 + row; if (v >= nV) v = nV - 1;
        const float* s = (g < 32) ? (feat + (size_t)v * 256 + g * 8)
                                  : (shp  + (size_t)v * 128 + (g - 32) * 8);
        const float4 a = ((const float4*)s)[0];
        const float4 b = ((const float4*)s)[1];
        hv8 h = { (_Float16)a.x, (_Float16)a.y, (_Float16)a.z, (_Float16)a.w,
                  (_Float16)b.x, (_Float16)b.y, (_Float16)b.z, (_Float16)b.w };
        *(hv8*)(&as[swzA(row, g * 8)]) = h;
    }
    f32x4 acc[4][4];
    #pragma unroll
    for (int mf = 0; mf < 4; ++mf)
        #pragma unroll
        for (int nf = 0; nf < 4; ++nf) acc[mf][nf] = (f32x4){0.f, 0.f, 0.f, 0.f};
    __syncthreads();

    auto loadA = [&](int t, hv8* dst) {
        #pragma unroll
        for (int mf = 0; mf < 4; ++mf)
            dst[mf] = *(const hv8*)(as + swzA(mf * 16 + l15, (t << 5) | (kq << 3)));
    };
    hv8 av[2][4];
    loadA(0, av[0]);
    #pragma unroll
    for (int t = 0; t < 12; ++t) {
        if (t + 1 < 12) loadA(t + 1, av[(t + 1) & 1]);
        const hv8* avt = av[t & 1];
        const hv8* bvt = bv[t % 3];
        __builtin_amdgcn_s_setprio(1);
        #pragma unroll
        for (int mf = 0; mf < 4; ++mf)
            #pragma unroll
            for (int nf = 0; nf < 4; ++nf)
                acc[mf][nf] = __builtin_amdgcn_mfma_f32_16x16x32_f16(avt[mf], bvt[nf], acc[mf][nf], 0, 0, 0);
        __builtin_amdgcn_s_setprio(0);
        if (t + 3 < 12) loadB(t + 3, bv[t % 3]);
    }
    #pragma unroll
    for (int mf = 0; mf < 4; ++mf)
        #pragma unroll
        for (int nf = 0; nf < 4; ++nf) {
            const int col = nbase + nf * 16 + l15;
            const int r0 = mf * 16 + (kq << 2);
            #pragma unroll
            for (int r = 0; r < 4; ++r) {
                const int v = n0 + r0 + r;
                if (v < nV) P[(size_t)v * 256 + col] = (_Float16)acc[mf][nf][r];
            }
        }
}

// ---- main fused pixel kernel ----
__global__ __launch_bounds__(256, 3)
void renderer(const int* __restrict__ pix, const float* __restrict__ bary,
              const int* __restrict__ faces,
              const _Float16* __restrict__ P,
              const float* __restrict__ color_bg,
              const float* __restrict__ b2g,
              const float* __restrict__ b3,
              const _Float16* __restrict__ w1T,
              const _Float16* __restrict__ w2T,
              const _Float16* __restrict__ w3T,
              const float* __restrict__ b1p,
              float* __restrict__ out)
{
    __shared__ _Float16 embs[64 * 64];    // 8 KB
    __shared__ _Float16 pb[64 * 256];     // 32 KB: blend -> h1 (in-place) -> h2
    __shared__ int   vidx[TILE_M][3];
    __shared__ float bcs[TILE_M][3];

    const int tid = threadIdx.x;
    const int cpx = gridDim.x >> 3;
    const int bid = (blockIdx.x & 7) * cpx + (blockIdx.x >> 3);   // XCD-aware
    const int n0  = bid * TILE_M;

    const int lane  = tid & 63;
    const int wv    = tid >> 6;
    const int nbase = wv << 6;
    const int l15   = lane & 15;
    const int kq    = lane >> 4;

    if (tid < TILE_M) {
        const int n = n0 + tid;
        const int face = pix[n];
        vidx[tid][0] = faces[face * 3 + 0];
        vidx[tid][1] = faces[face * 3 + 1];
        vidx[tid][2] = faces[face * 3 + 2];
        bcs[tid][0] = bary[n * 3 + 0];
        bcs[tid][1] = bary[n * 3 + 1];
        bcs[tid][2] = bary[n * 3 + 2];
    }
    __syncthreads();

    const int gp = tid >> 5;            // 0..7 : pixel within batch
    const int c8 = (tid & 31) << 3;     // col chunk (32 lanes cover a 512B row)

    // gather: 8 batches x 8 px; 2-deep ping-pong (T14 issue-early/consume-late)
    hv8 g0[3], g1[3];
    auto loadG = [&](hv8* g, const int b) {
        const int p = b * 8 + gp;
        g[0] = *(const hv8*)(P + (size_t)vidx[p][0] * 256 + c8);
        g[1] = *(const hv8*)(P + (size_t)vidx[p][1] * 256 + c8);
        g[2] = *(const hv8*)(P + (size_t)vidx[p][2] * 256 + c8);
    };
    auto blendG = [&](hv8* g, const int b) {
        const int p = b * 8 + gp;
        const _Float16 c0 = (_Float16)bcs[p][0];
        const _Float16 c1 = (_Float16)bcs[p][1];
        const _Float16 c2 = (_Float16)bcs[p][2];
        *(hv8*)(&pb[swzH(p, c8)]) = g[0] * c0 + g[1] * c1 + g[2] * c2;
    };

    loadG(g0, 0);
    loadG(g1, 1);

    // --- emb (NeRF embed of bary) -> embs; VALU hides batch-0/1 gather latency ---
    {
        const int p = tid >> 2;
        const int e16 = (tid & 3) << 4;
        const float c0 = bcs[p][0], c1 = bcs[p][1], c2 = bcs[p][2];
        #pragma unroll
        for (int hh = 0; hh < 2; ++hh) {
            hv8 h;
            #pragma unroll
            for (int i = 0; i < 8; ++i) {
                const int s = e16 + hh * 8 + i;
                float v;
                if (s < 3) v = (s == 0) ? c0 : ((s == 1) ? c1 : c2);
                else if (s < 63) {
                    const int q = s - 3;
                    const int f = q / 6;
                    const int rem = q - f * 6;
                    const int d = (rem >= 3) ? rem - 3 : rem;
                    const float bd = (d == 0) ? c0 : ((d == 1) ? c1 : c2);
                    const float arg = bd * (float)(1 << f);
                    v = (rem < 3) ? __sinf(arg) : __cosf(arg);
                } else v = 0.0f;
                h[i] = (_Float16)v;
            }
            *(hv8*)(&embs[swzE(p, e16 + hh * 8)]) = h;
        }
    }

    // drain the pipeline: blend b, immediately re-issue b+2 into the freed slot
    blendG(g0, 0); loadG(g0, 2);
    blendG(g1, 1); loadG(g1, 3);
    blendG(g0, 2); loadG(g0, 4);
    blendG(g1, 3); loadG(g1, 5);
    blendG(g0, 4); loadG(g0, 6);
    blendG(g1, 5); loadG(g1, 7);
    blendG(g0, 6);
    blendG(g1, 7);

    f32x4 acc[4][4];
    #pragma unroll
    for (int nf = 0; nf < 4; ++nf) {
        const float b = b1p[nbase + nf * 16 + l15];
        #pragma unroll
        for (int mf = 0; mf < 4; ++mf) acc[mf][nf] = (f32x4){b, b, b, b};
    }
    __syncthreads();   // embs + pb(blend) ready

    // --- layer-1 emb MFMA (2 tiles) ---
    #pragma unroll
    for (int t = 0; t < 2; ++t) {
        hv8 ave[4], bve[4];
        #pragma unroll
        for (int nf = 0; nf < 4; ++nf)
            bve[nf] = *(const hv8*)(w1T + (size_t)(nbase + nf * 16 + l15) * 448 + 384 + (t << 5) + (kq << 3));
        #pragma unroll
        for (int mf = 0; mf < 4; ++mf)
            ave[mf] = *(const hv8*)(embs + swzE(mf * 16 + l15, (t << 5) | (kq << 3)));
        __builtin_amdgcn_s_setprio(1);
        #pragma unroll
        for (int mf = 0; mf < 4; ++mf)
            #pragma unroll
            for (int nf = 0; nf < 4; ++nf)
                acc[mf][nf] = __builtin_amdgcn_mfma_f32_16x16x32_f16(ave[mf], bve[nf], acc[mf][nf], 0, 0, 0);
        __builtin_amdgcn_s_setprio(0);
    }

    // --- layer-1 epilogue: h1 = relu(acc + pb) IN-PLACE; acc = b2 ---
    #pragma unroll
    for (int mf = 0; mf < 4; ++mf)
        #pragma unroll
        for (int nf = 0; nf < 4; ++nf) {
            const int col = nbase + nf * 16 + l15;
            const int r0 = mf * 16 + (kq << 2);
            #pragma unroll
            for (int r = 0; r < 4; ++r) {
                const int sl = swzH(r0 + r, col);
                const float pv = (float)pb[sl];
                pb[sl] = (_Float16)fmaxf(acc[mf][nf][r] + pv, 0.0f);
            }
            const float b = b2g[col];
            acc[mf][nf] = (f32x4){b, b, b, b};
        }
    __syncthreads();   // h1 ready

    // --- layer-2: 8 K-tiles; per-tile fragment loads, compiler-scheduled ---
    const hv8* bp2[4];
    #pragma unroll
    for (int nf = 0; nf < 4; ++nf)
        bp2[nf] = (const hv8*)(w2T + (size_t)(nbase + nf * 16 + l15) * 256 + (kq << 3));
    #pragma unroll
    for (int t = 0; t < 8; ++t) {
        hv8 av[4], bv[4];
        #pragma unroll
        for (int nf = 0; nf < 4; ++nf) bv[nf] = bp2[nf][t << 2];
        #pragma unroll
        for (int mf = 0; mf < 4; ++mf)
            av[mf] = *(const hv8*)(pb + swzH(mf * 16 + l15, (t << 5) | (kq << 3)));
        __builtin_amdgcn_s_setprio(1);
        #pragma unroll
        for (int mf = 0; mf < 4; ++mf)
            #pragma unroll
            for (int nf = 0; nf < 4; ++nf)
                acc[mf][nf] = __builtin_amdgcn_mfma_f32_16x16x32_f16(av[mf], bv[nf], acc[mf][nf], 0, 0, 0);
        __builtin_amdgcn_s_setprio(0);
    }

    __syncthreads();   // all layer-2 A-reads done
    // --- h2 = relu(acc) -> pb ---
    #pragma unroll
    for (int mf = 0; mf < 4; ++mf)
        #pragma unroll
        for (int nf = 0; nf < 4; ++nf) {
            const int col = nbase + nf * 16 + l15;
            const int r0 = mf * 16 + (kq << 2);
            #pragma unroll
            for (int r = 0; r < 4; ++r)
                pb[swzH(r0 + r, col)] = (_Float16)fmaxf(acc[mf][nf][r], 0.0f);
        }

    // --- layer-3 B fragments; L2 latency hides under the barrier wait ---
    hv8 bw3[8];
    #pragma unroll
    for (int t = 0; t < 8; ++t)
        bw3[t] = *(const hv8*)(w3T + l15 * 256 + ((t << 5) | (kq << 3)));
    __syncthreads();

    // --- layer-3 MFMA: wave wv handles pixel rows [wv*16, wv*16+16) ---
    f32x4 acc3 = (f32x4){0.f, 0.f, 0.f, 0.f};
    #pragma unroll
    for (int t = 0; t < 8; ++t) {
        const hv8 av3 = *(const hv8*)(pb + swzH((wv << 4) + l15, (t << 5) | (kq << 3)));
        acc3 = __builtin_amdgcn_mfma_f32_16x16x32_f16(av3, bw3[t], acc3, 0, 0, 0);
    }
    if (l15 < 4) {
        const int ch = l15;
        #pragma unroll
        for (int r = 0; r < 4; ++r) {
            const int p = (wv << 4) + (kq << 2) + r;
            const int n = n0 + p;
            const bool m = pix[n] > 0;
            float v;
            if (ch == 3) v = m ? 1.0f : 0.0f;
            else         v = m ? (fmaxf(acc3[r] + b3[ch], 0.0f) - 1.0f)
                               : color_bg[(n >> 16) * 3 + ch];
            out[(size_t)n * 4 + ch] = v;
        }
    }
}

extern "C" void kernel_launch(void* const* d_in, const int* in_sizes, int n_in,
                              void* d_out, int out_size, void* d_ws, size_t ws_size,
                              hipStream_t stream) {
    const int*   pix      = (const int*)  d_in[0];
    const float* bary     = (const float*)d_in[1];
    const int*   faces    = (const int*)  d_in[2];
    const float* feature  = (const float*)d_in[3];
    const float* shapef   = (const float*)d_in[4];
    const float* color_bg = (const float*)d_in[5];
    const float* style    = (const float*)d_in[6];
    const float* w1       = (const float*)d_in[7];
    const float* b1       = (const float*)d_in[8];
    const float* w2       = (const float*)d_in[9];
    const float* b2       = (const float*)d_in[10];
    const float* w3       = (const float*)d_in[11];
    const float* b3       = (const float*)d_in[12];
    float* out = (float*)d_out;

    const int nV = in_sizes[3] / 256;                         // 50000 vertices

    char* ws = (char*)d_ws;
    _Float16* w1T  = (_Float16*)ws;                           // 229,376 B
    _Float16* w2T  = (_Float16*)(ws + 229376);                // 131,072 B
    float*    b1p  = (float*)   (ws + 360448);                // 1,024 B
    _Float16* w3T  = (_Float16*)(ws + 361472);                // 8,192 B
    _Float16* Ptab = (_Float16*)(ws + 369664);                // nV*256*2 = 25.6 MB

    hipLaunchKernelGGL(prep_weights, dim3(513), dim3(256), 0, stream,
                       style, w1, b1, w2, w3, w1T, w2T, w3T, b1p);
    hipLaunchKernelGGL(pgemm, dim3((nV + 63) / 64), dim3(256), 0, stream,
                       feature, shapef, w1T, Ptab, nV);

    const int npix = in_sizes[0];                             // 262144
    hipLaunchKernelGGL(renderer, dim3(npix / TILE_M), dim3(256), 0, stream,
                       pix, bary, faces, Ptab, color_bg,
                       b2, b3, w1T, w2T, w3T, b1p, out);
}

// Round 13
// 183.347 us; speedup vs baseline: 1.5195x; 1.0130x over previous
//
#include <hip/hip_runtime.h>
#include <math.h>

// DifferentiableMultiMLPRenderer — round 13: 8-wave block, acc[4][2].
// r12 lesson: concurrency-capped (12 waves/CU); acc[4][4]=64 AGPR blocks more.
// Now: TILE_M=64, 512 thr / 8 waves, wave-tile 64x32 -> acc[4][2]=32 AGPR,
// ~95 unified regs -> launch_bounds(512,4) (128 budget) spill-free, 2 blocks/CU
// = 16 waves/CU. Per-wave phases halve (12 gathers, 8 emb vals, 80 MFMA).

typedef _Float16 hv8 __attribute__((ext_vector_type(8)));
typedef __attribute__((ext_vector_type(4))) float f32x4;

#define TILE_M 64

__device__ inline int swzE(int row, int k) { return row * 64  + (k ^ ((row & 7) << 3)); }
__device__ inline int swzH(int row, int k) { return row * 256 + (k ^ ((row & 7) << 3)); }
__device__ inline int swzA(int row, int k) { return row * 384 + (k ^ ((row & 7) << 3)); }

// ---- prep: fold style into b1; build f16 weights: w1T (1/3 folded), w2T, w3T ----
__global__ __launch_bounds__(256)
void prep_weights(const float* __restrict__ style,
                  const float* __restrict__ w1, const float* __restrict__ b1,
                  const float* __restrict__ w2, const float* __restrict__ w3,
                  _Float16* __restrict__ w1T, _Float16* __restrict__ w2T,
                  _Float16* __restrict__ w3T, float* __restrict__ b1p)
{
    const int j = blockIdx.x;
    const int t = threadIdx.x;
    if (j < 256) {
        float part = style[t] * w1[(size_t)(447 + t) * 256 + j];
        #pragma unroll
        for (int off = 32; off; off >>= 1) part += __shfl_down(part, off, 64);
        __shared__ float red[4];
        if ((t & 63) == 0) red[t >> 6] = part;
        __syncthreads();
        if (t == 0) b1p[j] = b1[j] + red[0] + red[1] + red[2] + red[3];
        for (int k = t; k < 448; k += 256) {
            float v = (k < 447) ? w1[(size_t)k * 256 + j] : 0.0f;
            if (k < 384) v *= (1.0f / 3.0f);
            w1T[(size_t)j * 448 + k] = (_Float16)v;
        }
    } else if (j < 512) {
        const int jj = j - 256;
        w2T[(size_t)jj * 256 + t] = (_Float16)w2[(size_t)t * 256 + jj];
    } else {
        #pragma unroll
        for (int r = 0; r < 16; ++r)
            w3T[r * 256 + t] = (r < 3) ? (_Float16)w3[t * 3 + r] : (_Float16)0.0f;
    }
}

// ---- pgemm: P[v][j] = sum_k [feat|shape][v][k] * w1T[j][k] (1/3 folded) ----
__global__ __launch_bounds__(256, 2)
void pgemm(const float* __restrict__ feat, const float* __restrict__ shp,
           const _Float16* __restrict__ w1T, _Float16* __restrict__ P, int nV)
{
    __shared__ _Float16 as[64 * 384];   // 48 KB
    const int tid = threadIdx.x;
    const int n0 = blockIdx.x * 64;
    const int lane = tid & 63, wv = tid >> 6;
    const int nbase = wv << 6, l15 = lane & 15, kq = lane >> 4;

    const hv8* bp[4];
    #pragma unroll
    for (int nf = 0; nf < 4; ++nf)
        bp[nf] = (const hv8*)(w1T + (size_t)(nbase + nf * 16 + l15) * 448 + (kq << 3));
    hv8 bv[3][4];
    auto loadB = [&](int t, hv8* dst) {
        #pragma unroll
        for (int nf = 0; nf < 4; ++nf) dst[nf] = bp[nf][t << 2];
    };
    loadB(0, bv[0]); loadB(1, bv[1]); loadB(2, bv[2]);

    #pragma unroll
    for (int i = 0; i < 12; ++i) {
        const int id = tid + i * 256;
        const int row = id / 48;
        const int g = id - row * 48;
        int v = n0 + row; if (v >= nV) v = nV - 1;
        const float* s = (g < 32) ? (feat + (size_t)v * 256 + g * 8)
                                  : (shp  + (size_t)v * 128 + (g - 32) * 8);
        const float4 a = ((const float4*)s)[0];
        const float4 b = ((const float4*)s)[1];
        hv8 h = { (_Float16)a.x, (_Float16)a.y, (_Float16)a.z, (_Float16)a.w,
                  (_Float16)b.x, (_Float16)b.y, (_Float16)b.z, (_Float16)b.w };
        *(hv8*)(&as[swzA(row, g * 8)]) = h;
    }
    f32x4 acc[4][4];
    #pragma unroll
    for (int mf = 0; mf < 4; ++mf)
        #pragma unroll
        for (int nf = 0; nf < 4; ++nf) acc[mf][nf] = (f32x4){0.f, 0.f, 0.f, 0.f};
    __syncthreads();

    auto loadA = [&](int t, hv8* dst) {
        #pragma unroll
        for (int mf = 0; mf < 4; ++mf)
            dst[mf] = *(const hv8*)(as + swzA(mf * 16 + l15, (t << 5) | (kq << 3)));
    };
    hv8 av[2][4];
    loadA(0, av[0]);
    #pragma unroll
    for (int t = 0; t < 12; ++t) {
        if (t + 1 < 12) loadA(t + 1, av[(t + 1) & 1]);
        const hv8* avt = av[t & 1];
        const hv8* bvt = bv[t % 3];
        __builtin_amdgcn_s_setprio(1);
        #pragma unroll
        for (int mf = 0; mf < 4; ++mf)
            #pragma unroll
            for (int nf = 0; nf < 4; ++nf)
                acc[mf][nf] = __builtin_amdgcn_mfma_f32_16x16x32_f16(avt[mf], bvt[nf], acc[mf][nf], 0, 0, 0);
        __builtin_amdgcn_s_setprio(0);
        if (t + 3 < 12) loadB(t + 3, bv[t % 3]);
    }
    #pragma unroll
    for (int mf = 0; mf < 4; ++mf)
        #pragma unroll
        for (int nf = 0; nf < 4; ++nf) {
            const int col = nbase + nf * 16 + l15;
            const int r0 = mf * 16 + (kq << 2);
            #pragma unroll
            for (int r = 0; r < 4; ++r) {
                const int v = n0 + r0 + r;
                if (v < nV) P[(size_t)v * 256 + col] = (_Float16)acc[mf][nf][r];
            }
        }
}

// ---- main fused pixel kernel: 512 threads, 8 waves, wave-tile 64x32 ----
__global__ __launch_bounds__(512, 4)
void renderer(const int* __restrict__ pix, const float* __restrict__ bary,
              const int* __restrict__ faces,
              const _Float16* __restrict__ P,
              const float* __restrict__ color_bg,
              const float* __restrict__ b2g,
              const float* __restrict__ b3,
              const _Float16* __restrict__ w1T,
              const _Float16* __restrict__ w2T,
              const _Float16* __restrict__ w3T,
              const float* __restrict__ b1p,
              float* __restrict__ out)
{
    __shared__ _Float16 embs[64 * 64];    // 8 KB
    __shared__ _Float16 pb[64 * 256];     // 32 KB: blend -> h1 (in-place) -> h2
    __shared__ int   vidx[TILE_M][3];
    __shared__ float bcs[TILE_M][3];

    const int tid = threadIdx.x;
    const int cpx = gridDim.x >> 3;
    const int bid = (blockIdx.x & 7) * cpx + (blockIdx.x >> 3);   // XCD-aware
    const int n0  = bid * TILE_M;

    const int lane  = tid & 63;
    const int wv    = tid >> 6;          // 0..7
    const int nbase = wv << 5;           // 32 cols per wave
    const int l15   = lane & 15;
    const int kq    = lane >> 4;

    if (tid < TILE_M) {
        const int n = n0 + tid;
        const int face = pix[n];
        vidx[tid][0] = faces[face * 3 + 0];
        vidx[tid][1] = faces[face * 3 + 1];
        vidx[tid][2] = faces[face * 3 + 2];
        bcs[tid][0] = bary[n * 3 + 0];
        bcs[tid][1] = bary[n * 3 + 1];
        bcs[tid][2] = bary[n * 3 + 2];
    }
    __syncthreads();

    const int gp = tid >> 5;            // 0..15 : pixel within batch
    const int c8 = (tid & 31) << 3;     // col chunk (32 lanes cover a 512B row)

    // gather: 4 batches x 16 px; 2-deep ping-pong (T14); 12 loads/thread
    hv8 g0[3], g1[3];
    auto loadG = [&](hv8* g, const int b) {
        const int p = b * 16 + gp;
        g[0] = *(const hv8*)(P + (size_t)vidx[p][0] * 256 + c8);
        g[1] = *(const hv8*)(P + (size_t)vidx[p][1] * 256 + c8);
        g[2] = *(const hv8*)(P + (size_t)vidx[p][2] * 256 + c8);
    };
    auto blendG = [&](hv8* g, const int b) {
        const int p = b * 16 + gp;
        const _Float16 c0 = (_Float16)bcs[p][0];
        const _Float16 c1 = (_Float16)bcs[p][1];
        const _Float16 c2 = (_Float16)bcs[p][2];
        *(hv8*)(&pb[swzH(p, c8)]) = g[0] * c0 + g[1] * c1 + g[2] * c2;
    };

    loadG(g0, 0);
    loadG(g1, 1);

    // --- emb (NeRF embed of bary) -> embs; 8 vals/thread, one 16B store ---
    {
        const int p = tid >> 3;            // 0..63
        const int e8 = (tid & 7) << 3;     // slot base
        const float c0 = bcs[p][0], c1 = bcs[p][1], c2 = bcs[p][2];
        hv8 h;
        #pragma unroll
        for (int i = 0; i < 8; ++i) {
            const int s = e8 + i;
            float v;
            if (s < 3) v = (s == 0) ? c0 : ((s == 1) ? c1 : c2);
            else if (s < 63) {
                const int q = s - 3;
                const int f = q / 6;
                const int rem = q - f * 6;
                const int d = (rem >= 3) ? rem - 3 : rem;
                const float bd = (d == 0) ? c0 : ((d == 1) ? c1 : c2);
                const float arg = bd * (float)(1 << f);
                v = (rem < 3) ? __sinf(arg) : __cosf(arg);
            } else v = 0.0f;
            h[i] = (_Float16)v;
        }
        *(hv8*)(&embs[swzE(p, e8)]) = h;
    }

    // drain: blend b, re-issue b+2 into the freed slot
    blendG(g0, 0); loadG(g0, 2);
    blendG(g1, 1); loadG(g1, 3);
    blendG(g0, 2);
    blendG(g1, 3);

    f32x4 acc[4][2];
    #pragma unroll
    for (int nf = 0; nf < 2; ++nf) {
        const float b = b1p[nbase + nf * 16 + l15];
        #pragma unroll
        for (int mf = 0; mf < 4; ++mf) acc[mf][nf] = (f32x4){b, b, b, b};
    }
    __syncthreads();   // embs + pb(blend) ready

    // --- layer-1 emb MFMA (2 tiles, 8 MFMA each) ---
    #pragma unroll
    for (int t = 0; t < 2; ++t) {
        hv8 ave[4], bve[2];
        #pragma unroll
        for (int nf = 0; nf < 2; ++nf)
            bve[nf] = *(const hv8*)(w1T + (size_t)(nbase + nf * 16 + l15) * 448 + 384 + (t << 5) + (kq << 3));
        #pragma unroll
        for (int mf = 0; mf < 4; ++mf)
            ave[mf] = *(const hv8*)(embs + swzE(mf * 16 + l15, (t << 5) | (kq << 3)));
        __builtin_amdgcn_s_setprio(1);
        #pragma unroll
        for (int mf = 0; mf < 4; ++mf)
            #pragma unroll
            for (int nf = 0; nf < 2; ++nf)
                acc[mf][nf] = __builtin_amdgcn_mfma_f32_16x16x32_f16(ave[mf], bve[nf], acc[mf][nf], 0, 0, 0);
        __builtin_amdgcn_s_setprio(0);
    }

    // --- layer-1 epilogue: h1 = relu(acc + pb) IN-PLACE; acc = b2 ---
    #pragma unroll
    for (int mf = 0; mf < 4; ++mf)
        #pragma unroll
        for (int nf = 0; nf < 2; ++nf) {
            const int col = nbase + nf * 16 + l15;
            const int r0 = mf * 16 + (kq << 2);
            #pragma unroll
            for (int r = 0; r < 4; ++r) {
                const int sl = swzH(r0 + r, col);
                const float pv = (float)pb[sl];
                pb[sl] = (_Float16)fmaxf(acc[mf][nf][r] + pv, 0.0f);
            }
            const float b = b2g[col];
            acc[mf][nf] = (f32x4){b, b, b, b};
        }
    __syncthreads();   // h1 ready

    // --- layer-2: 8 K-tiles; per-tile fragment loads, compiler-scheduled ---
    const hv8* bp2[2];
    #pragma unroll
    for (int nf = 0; nf < 2; ++nf)
        bp2[nf] = (const hv8*)(w2T + (size_t)(nbase + nf * 16 + l15) * 256 + (kq << 3));
    #pragma unroll
    for (int t = 0; t < 8; ++t) {
        hv8 av[4], bv[2];
        #pragma unroll
        for (int nf = 0; nf < 2; ++nf) bv[nf] = bp2[nf][t << 2];
        #pragma unroll
        for (int mf = 0; mf < 4; ++mf)
            av[mf] = *(const hv8*)(pb + swzH(mf * 16 + l15, (t << 5) | (kq << 3)));
        __builtin_amdgcn_s_setprio(1);
        #pragma unroll
        for (int mf = 0; mf < 4; ++mf)
            #pragma unroll
            for (int nf = 0; nf < 2; ++nf)
                acc[mf][nf] = __builtin_amdgcn_mfma_f32_16x16x32_f16(av[mf], bv[nf], acc[mf][nf], 0, 0, 0);
        __builtin_amdgcn_s_setprio(0);
    }

    __syncthreads();   // all layer-2 A-reads done
    // --- h2 = relu(acc) -> pb ---
    #pragma unroll
    for (int mf = 0; mf < 4; ++mf)
        #pragma unroll
        for (int nf = 0; nf < 2; ++nf) {
            const int col = nbase + nf * 16 + l15;
            const int r0 = mf * 16 + (kq << 2);
            #pragma unroll
            for (int r = 0; r < 4; ++r)
                pb[swzH(r0 + r, col)] = (_Float16)fmaxf(acc[mf][nf][r], 0.0f);
        }

    // --- layer-3 B fragments (waves 0-3 only); hide under barrier wait ---
    hv8 bw3[8];
    if (wv < 4) {
        #pragma unroll
        for (int t = 0; t < 8; ++t)
            bw3[t] = *(const hv8*)(w3T + l15 * 256 + ((t << 5) | (kq << 3)));
    }
    __syncthreads();

    // --- layer-3 MFMA: wave wv (0..3) handles pixel rows [wv*16, wv*16+16) ---
    if (wv < 4) {
        f32x4 acc3 = (f32x4){0.f, 0.f, 0.f, 0.f};
        #pragma unroll
        for (int t = 0; t < 8; ++t) {
            const hv8 av3 = *(const hv8*)(pb + swzH((wv << 4) + l15, (t << 5) | (kq << 3)));
            acc3 = __builtin_amdgcn_mfma_f32_16x16x32_f16(av3, bw3[t], acc3, 0, 0, 0);
        }
        if (l15 < 4) {
            const int ch = l15;
            #pragma unroll
            for (int r = 0; r < 4; ++r) {
                const int p = (wv << 4) + (kq << 2) + r;
                const int n = n0 + p;
                const bool m = pix[n] > 0;
                float v;
                if (ch == 3) v = m ? 1.0f : 0.0f;
                else         v = m ? (fmaxf(acc3[r] + b3[ch], 0.0f) - 1.0f)
                                   : color_bg[(n >> 16) * 3 + ch];
                out[(size_t)n * 4 + ch] = v;
            }
        }
    }
}

extern "C" void kernel_launch(void* const* d_in, const int* in_sizes, int n_in,
                              void* d_out, int out_size, void* d_ws, size_t ws_size,
                              hipStream_t stream) {
    const int*   pix      = (const int*)  d_in[0];
    const float* bary     = (const float*)d_in[1];
    const int*   faces    = (const int*)  d_in[2];
    const float* feature  = (const float*)d_in[3];
    const float* shapef   = (const float*)d_in[4];
    const float* color_bg = (const float*)d_in[5];
    const float* style    = (const float*)d_in[6];
    const float* w1       = (const float*)d_in[7];
    const float* b1       = (const float*)d_in[8];
    const float* w2       = (const float*)d_in[9];
    const float* b2       = (const float*)d_in[10];
    const float* w3       = (const float*)d_in[11];
    const float* b3       = (const float*)d_in[12];
    float* out = (float*)d_out;

    const int nV = in_sizes[3] / 256;                         // 50000 vertices

    char* ws = (char*)d_ws;
    _Float16* w1T  = (_Float16*)ws;                           // 229,376 B
    _Float16* w2T  = (_Float16*)(ws + 229376);                // 131,072 B
    float*    b1p  = (float*)   (ws + 360448);                // 1,024 B
    _Float16* w3T  = (_Float16*)(ws + 361472);                // 8,192 B
    _Float16* Ptab = (_Float16*)(ws + 369664);                // nV*256*2 = 25.6 MB

    hipLaunchKernelGGL(prep_weights, dim3(513), dim3(256), 0, stream,
                       style, w1, b1, w2, w3, w1T, w2T, w3T, b1p);
    hipLaunchKernelGGL(pgemm, dim3((nV + 63) / 64), dim3(256), 0, stream,
                       feature, shapef, w1T, Ptab, nV);

    const int npix = in_sizes[0];                             // 262144
    hipLaunchKernelGGL(renderer, dim3(npix / TILE_M), dim3(512), 0, stream,
                       pix, bary, faces, Ptab, color_bg,
                       b2, b3, w1T, w2T, w3T, b1p, out);
}